// Round 12
// baseline (501.295 us; speedup 1.0000x reference)
//
#include <hip/hip_runtime.h>
#include <math.h>

#define SEQ 1024
#define BATCH 4
#define DMODEL 512
#define NHEAD 8
#define DK 64
#define DFF 2048
#define U_TOP 34
#define ROWS (BATCH * SEQ)

typedef unsigned short ushort_t;
typedef __attribute__((ext_vector_type(8))) short short8;
typedef __attribute__((ext_vector_type(4))) float float4v;
typedef __attribute__((ext_vector_type(2))) _Float16 h2v;

__device__ inline ushort_t f2bf(float f) {
  unsigned u = __float_as_uint(f);
  unsigned r = u + 0x7fffu + ((u >> 16) & 1u);
  return (ushort_t)(r >> 16);
}
__device__ inline float bf2f(ushort_t u) {
  return __uint_as_float((unsigned)u << 16);
}
// ordered-uint key -> float (rare >64-candidate fallback only)
__device__ inline float keyinv(unsigned cand) {
  unsigned fb = (cand & 0x80000000u) ? (cand ^ 0x80000000u) : ~cand;
  return __uint_as_float(fb);
}

union H16 { _Float16 h; unsigned short u; };
__device__ inline unsigned short h2u(float f) {
  H16 t; t.h = (_Float16)f; return t.u;
}
__device__ inline float u2h(unsigned short u) {
  H16 t; t.u = u; return (float)t.h;
}
__device__ inline _Float16 u2h16(unsigned short u) {
  H16 t; t.u = u; return t.h;
}
// fp16 bits -> 16-bit ordered key (unsigned compare == float compare)
__device__ inline unsigned okey16(unsigned b) {
  return (b ^ (0x8000u | ((b >> 15) * 0x7FFFu))) & 0xFFFFu;
}
// inverse of okey16
__device__ inline unsigned short ikey16(unsigned k) {
  return (unsigned short)(k ^ ((k >> 15) ? 0x8000u : 0xFFFFu));
}
__device__ inline int mbcnt64(unsigned long long m) {
  int lo = __builtin_amdgcn_mbcnt_lo((unsigned)m, 0);
  return __builtin_amdgcn_mbcnt_hi((unsigned)(m >> 32), lo);
}

__device__ inline void glds16(const void* g, void* l) {
  __builtin_amdgcn_global_load_lds(
      (const __attribute__((address_space(1))) unsigned int*)g,
      (__attribute__((address_space(3))) unsigned int*)l, 16, 0, 0);
}

// packed fp16 max (v_pk_max_f16)
__device__ inline unsigned pkmax(unsigned a, unsigned b) {
  return __builtin_bit_cast(unsigned, __builtin_elementwise_max(
      __builtin_bit_cast(h2v, a), __builtin_bit_cast(h2v, b)));
}

// ---------------------------------------------------------------------------
// bf16 MFMA GEMM, 128xBN tile (BN in {64,128}), BK=64 staged as TWO adjacent
// BK=32 sub-tiles, 2-phase double-buffered K-loop: stage(t+1) issued BEFORE
// the ds_read+MFMA of tile t; ONE barrier per 64-wide K-step.
// BN=64: 48KB LDS -> 3 blocks/CU (QKV). BN=128: 64KB -> 2 blocks/CU but
// 250B staged/MFMA (FFN1, N=2048).
// XCD swizzle: each XCD owns a band of row-tiles (A fetched once per band).
// SPLIT=1 (QKV): Bt has 1536 rows (Wq|Wk|Wv); z=bn>>9 routes output/bias.
// Requires gridDim.y % 8 == 0 and K % 64 == 0.
// ---------------------------------------------------------------------------
template <int RELU, int SPLIT, int BN>
__global__ __launch_bounds__(256) void gemmT(
    const ushort_t* __restrict__ A, const short* __restrict__ Bt,
    const float* __restrict__ b0, const float* __restrict__ b1,
    const float* __restrict__ b2, ushort_t* __restrict__ Cout,
    int K, int N, int zCstride) {
  constexpr int NT = BN / 32;  // n-tiles per wave (wave covers BN/2 cols)
  __shared__ short As[2][2][128 * 32];
  __shared__ short Bs[2][2][BN * 32];

  const int tid = threadIdx.x;
  const int lane = tid & 63, w = tid >> 6;
  const int wm = w >> 1, wn = w & 1;
  const int quad = lane >> 4, r16 = lane & 15;

  // XCD-affinity block swizzle (round-robin id%8 -> XCD heuristic)
  const int id = blockIdx.y * gridDim.x + blockIdx.x;
  const int xcd = id & 7;
  const int loc = id >> 3;
  const int rpx = gridDim.y >> 3;  // row-tiles per XCD
  const int bm = (xcd * rpx + (loc % rpx)) * 128;
  const int bn = (loc / rpx) * BN;

  const int srow = lane >> 2, skseg = lane & 3;
  const ushort_t* Ag0 = A + (size_t)(bm + w * 16 + srow) * K + skseg * 8;
  const ushort_t* Ag1 = Ag0 + (size_t)64 * K;
  const short* Bg0 = Bt + (size_t)(bn + w * 16 + srow) * K + skseg * 8;
  const short* Bg1 = Bg0 + (size_t)64 * K;
  const int aoff0 = (w * 16) * 32;
  const int aoff1 = (64 + w * 16) * 32;
  const int boff0 = (w * 16) * 32;
  const int boff1 = (64 + w * 16) * 32;

  float4v acc[4][NT];
#pragma unroll
  for (int m = 0; m < 4; ++m)
#pragma unroll
    for (int n = 0; n < NT; ++n) acc[m][n] = (float4v){0.f, 0.f, 0.f, 0.f};

  // stage one 64-wide K-tile (two 32-wide halves) into buffer bi
  auto stage = [&](int k0, int bi) {
#pragma unroll
    for (int hh = 0; hh < 2; ++hh) {
      glds16(Ag0 + k0 + hh * 32, &As[bi][hh][aoff0]);
      glds16(Ag1 + k0 + hh * 32, &As[bi][hh][aoff1]);
      glds16(Bg0 + k0 + hh * 32, &Bs[bi][hh][boff0]);
      if (BN == 128) glds16(Bg1 + k0 + hh * 32, &Bs[bi][hh][boff1]);
    }
  };

  stage(0, 0);
  __syncthreads();  // compiler emits vmcnt(0) before barrier

  int cur = 0;
  for (int k0 = 0; k0 < K; k0 += 64) {
    if (k0 + 64 < K) stage(k0 + 64, cur ^ 1);

#pragma unroll
    for (int hh = 0; hh < 2; ++hh) {
      short8 af[4], bfr[NT];
#pragma unroll
      for (int m = 0; m < 4; ++m)
        af[m] = *(const short8*)&As[cur][hh][(wm * 64 + m * 16 + r16) * 32 +
                                             quad * 8];
#pragma unroll
      for (int n = 0; n < NT; ++n)
        bfr[n] = *(const short8*)&Bs[cur][hh][(wn * (BN / 2) + n * 16 + r16) *
                                                  32 +
                                              quad * 8];
#pragma unroll
      for (int m = 0; m < 4; ++m)
#pragma unroll
        for (int n = 0; n < NT; ++n)
          acc[m][n] = __builtin_amdgcn_mfma_f32_16x16x32_bf16(
              af[m], bfr[n], acc[m][n], 0, 0, 0);
    }
    __syncthreads();  // drains new stage + ds_reads; 1 barrier per 64-K step
    cur ^= 1;
  }

  const int z = SPLIT ? (bn >> 9) : 0;
  const float* bias = (z == 0) ? b0 : (z == 1 ? b1 : b2);
  const int cbase = SPLIT ? (bn & 511) : bn;
  const int strideN = SPLIT ? 512 : N;
  ushort_t* C = Cout + (SPLIT ? (size_t)z * zCstride : (size_t)0);

  float bias_n[NT];
#pragma unroll
  for (int n = 0; n < NT; ++n)
    bias_n[n] = bias[cbase + wn * (BN / 2) + n * 16 + r16];

#pragma unroll
  for (int m = 0; m < 4; ++m) {
#pragma unroll
    for (int n = 0; n < NT; ++n) {
      int col = cbase + wn * (BN / 2) + n * 16 + r16;
#pragma unroll
      for (int reg = 0; reg < 4; ++reg) {
        int row = bm + wm * 64 + m * 16 + quad * 4 + reg;
        float v = acc[m][n][reg] + bias_n[n];
        if (RELU) v = fmaxf(v, 0.f);
        C[(size_t)row * strideN + col] = f2bf(v);
      }
    }
  }
}

// ---------------------------------------------------------------------------
// Split-K bf16 MFMA GEMM, 128xBN tile over K-range [z*Ks, (z+1)*Ks).
// Same BK=64 two-half 2-phase K-loop as gemmT. Requires Ks % 64 == 0.
// Writes bf16 partials to pout + z*2097152 (N fixed 512). Bias on z==0.
// ---------------------------------------------------------------------------
template <int BN>
__global__ __launch_bounds__(256) void gemmskT(
    const ushort_t* __restrict__ A, const short* __restrict__ Bt,
    const float* __restrict__ bias, ushort_t* __restrict__ pout,
    int K, int Ks) {
  constexpr int NT = BN / 32;
  __shared__ short As[2][2][128 * 32];
  __shared__ short Bs[2][2][BN * 32];

  const int tid = threadIdx.x;
  const int lane = tid & 63, w = tid >> 6;
  const int wm = w >> 1, wn = w & 1;
  const int quad = lane >> 4, r16 = lane & 15;

  const int id = blockIdx.y * gridDim.x + blockIdx.x;
  const int xcd = id & 7;
  const int loc = id >> 3;
  const int rpx = gridDim.y >> 3;
  const int bm = (xcd * rpx + (loc % rpx)) * 128;
  const int bn = (loc / rpx) * BN;
  const int z = blockIdx.z;
  const int koff = z * Ks;

  const int srow = lane >> 2, skseg = lane & 3;
  const ushort_t* Ag0 =
      A + (size_t)(bm + w * 16 + srow) * K + skseg * 8 + koff;
  const ushort_t* Ag1 = Ag0 + (size_t)64 * K;
  const short* Bg0 = Bt + (size_t)(bn + w * 16 + srow) * K + skseg * 8 + koff;
  const short* Bg1 = Bg0 + (size_t)64 * K;
  const int aoff0 = (w * 16) * 32;
  const int aoff1 = (64 + w * 16) * 32;
  const int boff0 = (w * 16) * 32;
  const int boff1 = (64 + w * 16) * 32;

  float4v acc[4][NT];
#pragma unroll
  for (int m = 0; m < 4; ++m)
#pragma unroll
    for (int n = 0; n < NT; ++n) acc[m][n] = (float4v){0.f, 0.f, 0.f, 0.f};

  auto stage = [&](int k0, int bi) {
#pragma unroll
    for (int hh = 0; hh < 2; ++hh) {
      glds16(Ag0 + k0 + hh * 32, &As[bi][hh][aoff0]);
      glds16(Ag1 + k0 + hh * 32, &As[bi][hh][aoff1]);
      glds16(Bg0 + k0 + hh * 32, &Bs[bi][hh][boff0]);
      if (BN == 128) glds16(Bg1 + k0 + hh * 32, &Bs[bi][hh][boff1]);
    }
  };

  stage(0, 0);
  __syncthreads();

  int cur = 0;
  for (int k0 = 0; k0 < Ks; k0 += 64) {
    if (k0 + 64 < Ks) stage(k0 + 64, cur ^ 1);

#pragma unroll
    for (int hh = 0; hh < 2; ++hh) {
      short8 af[4], bfr[NT];
#pragma unroll
      for (int m = 0; m < 4; ++m)
        af[m] = *(const short8*)&As[cur][hh][(wm * 64 + m * 16 + r16) * 32 +
                                             quad * 8];
#pragma unroll
      for (int n = 0; n < NT; ++n)
        bfr[n] = *(const short8*)&Bs[cur][hh][(wn * (BN / 2) + n * 16 + r16) *
                                                  32 +
                                              quad * 8];
#pragma unroll
      for (int m = 0; m < 4; ++m)
#pragma unroll
        for (int n = 0; n < NT; ++n)
          acc[m][n] = __builtin_amdgcn_mfma_f32_16x16x32_bf16(
              af[m], bfr[n], acc[m][n], 0, 0, 0);
    }
    __syncthreads();
    cur ^= 1;
  }

  ushort_t* P = pout + (size_t)z * 2097152;
  float bias_n[NT];
#pragma unroll
  for (int n = 0; n < NT; ++n)
    bias_n[n] = (z == 0) ? bias[bn + wn * (BN / 2) + n * 16 + r16] : 0.f;

#pragma unroll
  for (int m = 0; m < 4; ++m) {
#pragma unroll
    for (int n = 0; n < NT; ++n) {
      int col = bn + wn * (BN / 2) + n * 16 + r16;
#pragma unroll
      for (int reg = 0; reg < 4; ++reg) {
        int row = bm + wm * 64 + m * 16 + quad * 4 + reg;
        float v = acc[m][n][reg] + bias_n[n];
        P[(size_t)row * 512 + col] = f2bf(v);
      }
    }
  }
}

// ---------------------------------------------------------------------------
// bf16 MFMA GEMM, tile 64x64 (embed + decode only), BK=64 two-half 2-phase.
// EPI 0: none. EPI 2: v = v*sqrt(512) + positional encoding (embed).
// Requires K % 64 == 0 (embed K=128, decode K=512).
// ---------------------------------------------------------------------------
template <int RELU, int OUTBF16, int EPI, int ADDC>
__global__ __launch_bounds__(256) void gemm64(
    const ushort_t* __restrict__ A, const short* __restrict__ Bt,
    const float* __restrict__ bias, void* __restrict__ Cout,
    const ushort_t* __restrict__ Cadd, int K, int N) {
  __shared__ short As[2][2][64 * 32];
  __shared__ short Bs[2][2][64 * 32];

  const int tid = threadIdx.x;
  const int lane = tid & 63, w = tid >> 6;
  const int wm = w >> 1, wn = w & 1;
  const int quad = lane >> 4, r16 = lane & 15;
  const int bm = blockIdx.y * 64, bn = blockIdx.x * 64;

  const int srow = tid >> 2, skseg = tid & 3;
  const ushort_t* Ag = A + (size_t)(bm + srow) * K + skseg * 8;
  const short* Bg = Bt + (size_t)(bn + srow) * K + skseg * 8;
  const int loff = w * 512;

  float4v acc[2][2];
#pragma unroll
  for (int m = 0; m < 2; ++m)
#pragma unroll
    for (int n = 0; n < 2; ++n) acc[m][n] = (float4v){0.f, 0.f, 0.f, 0.f};

  auto stage = [&](int k0, int bi) {
#pragma unroll
    for (int hh = 0; hh < 2; ++hh) {
      glds16(Ag + k0 + hh * 32, &As[bi][hh][loff]);
      glds16(Bg + k0 + hh * 32, &Bs[bi][hh][loff]);
    }
  };

  stage(0, 0);
  __syncthreads();

  int cur = 0;
  for (int k0 = 0; k0 < K; k0 += 64) {
    if (k0 + 64 < K) stage(k0 + 64, cur ^ 1);

#pragma unroll
    for (int hh = 0; hh < 2; ++hh) {
      short8 af[2], bfr[2];
#pragma unroll
      for (int m = 0; m < 2; ++m)
        af[m] = *(const short8*)&As[cur][hh][(wm * 32 + m * 16 + r16) * 32 +
                                             quad * 8];
#pragma unroll
      for (int n = 0; n < 2; ++n)
        bfr[n] = *(const short8*)&Bs[cur][hh][(wn * 32 + n * 16 + r16) * 32 +
                                              quad * 8];
#pragma unroll
      for (int m = 0; m < 2; ++m)
#pragma unroll
        for (int n = 0; n < 2; ++n)
          acc[m][n] = __builtin_amdgcn_mfma_f32_16x16x32_bf16(
              af[m], bfr[n], acc[m][n], 0, 0, 0);
    }
    __syncthreads();
    cur ^= 1;
  }

  const float pe_c = (float)(-9.210340371976184 / 512.0);
  const float sqrtd = 22.62741699796952f;

  float bias_n[2];
#pragma unroll
  for (int n = 0; n < 2; ++n) bias_n[n] = bias[bn + wn * 32 + n * 16 + r16];

#pragma unroll
  for (int m = 0; m < 2; ++m) {
#pragma unroll
    for (int n = 0; n < 2; ++n) {
      int col = bn + wn * 32 + n * 16 + r16;
#pragma unroll
      for (int reg = 0; reg < 4; ++reg) {
        int row = bm + wm * 32 + m * 16 + quad * 4 + reg;
        float v = acc[m][n][reg] + bias_n[n];
        if (RELU) v = fmaxf(v, 0.f);
        if (EPI == 2) {
          int pos = row & (SEQ - 1);
          float e = __expf((float)(col & ~1) * pe_c);
          float arg = (float)pos * e;
          v = v * sqrtd + ((col & 1) ? __cosf(arg) : __sinf(arg));
        }
        if (ADDC) v += bf2f(Cadd[(size_t)row * N + col]);
        if (OUTBF16) {
          ((ushort_t*)Cout)[(size_t)row * N + col] = f2bf(v);
        } else {
          ((float*)Cout)[(size_t)row * N + col] = v;
        }
      }
    }
  }
}

// ---------------------------------------------------------------------------
// All weights (3 layers + emb + dec): W[K][N] f32 -> Wt[N][K] bf16, 1 launch.
// ---------------------------------------------------------------------------
__global__ __launch_bounds__(256) void convert_all(
    const float* __restrict__ Wq, const float* __restrict__ Wk,
    const float* __restrict__ Wv, const float* __restrict__ Wo,
    const float* __restrict__ W1, const float* __restrict__ W2,
    const float* __restrict__ W_emb, const float* __restrict__ W_dec,
    short* __restrict__ wt) {
  __shared__ float t[32][33];
  int id = blockIdx.x;
  const float* src;
  short* dst;
  int K, N, tk, tn;
  if (id < 9216) {
    int lay = id / 3072, r = id % 3072;
    short* wl = wt + (size_t)lay * 3145728;
    const size_t wsz = 512 * 512;
    if (r < 1024) {
      int wi = r >> 8, tile = r & 255;
      const float* base = (wi == 0) ? Wq : (wi == 1) ? Wk : (wi == 2) ? Wv : Wo;
      src = base + lay * wsz;
      dst = wl + wi * 262144;
      K = 512; N = 512; tk = tile >> 4; tn = tile & 15;
    } else if (r < 2048) {
      int tile = r - 1024;
      src = W1 + (size_t)lay * 512 * 2048;
      dst = wl + 1048576;
      K = 512; N = 2048; tk = tile >> 6; tn = tile & 63;
    } else {
      int tile = r - 2048;
      src = W2 + (size_t)lay * 2048 * 512;
      dst = wl + 2097152;
      K = 2048; N = 512; tk = tile >> 4; tn = tile & 15;
    }
  } else {
    int r = id - 9216;
    if (r < 64) {
      src = W_emb; dst = wt + 9437184; K = 128; N = 512; tk = r >> 4; tn = r & 15;
    } else {
      r -= 64;
      src = W_dec; dst = wt + 9502720; K = 512; N = 64; tk = r >> 1; tn = r & 1;
    }
  }
  const int k0 = tk * 32, n0 = tn * 32;
  const int tx = threadIdx.x, ty = threadIdx.y;
#pragma unroll
  for (int i = 0; i < 4; ++i) {
    int r = ty + i * 8;
    t[r][tx] = src[(size_t)(k0 + r) * N + n0 + tx];
  }
  __syncthreads();
#pragma unroll
  for (int i = 0; i < 4; ++i) {
    int r = ty + i * 8;
    dst[(size_t)(n0 + r) * K + k0 + tx] = (short)f2bf(t[tx][r]);
  }
}

__global__ __launch_bounds__(256) void f32_to_bf16_kernel(
    const float* __restrict__ src, ushort_t* __restrict__ dst) {
  int i = blockIdx.x * blockDim.x + threadIdx.x;
  float4 v = ((const float4*)src)[i];
  ushort4 o;
  o.x = f2bf(v.x); o.y = f2bf(v.y); o.z = f2bf(v.z); o.w = f2bf(v.w);
  ((ushort4*)dst)[i] = o;
}

// ---------------------------------------------------------------------------
// Split-K reduce + residual + LayerNorm: hb = LN(pa + pb + hb) * g + b.
// ---------------------------------------------------------------------------
__global__ __launch_bounds__(256) void ln_red_kernel(
    const ushort_t* __restrict__ pa, const ushort_t* __restrict__ pb,
    const float* __restrict__ g, const float* __restrict__ bb,
    ushort_t* __restrict__ hb) {
  const int row = blockIdx.x * 4 + (threadIdx.x >> 6);
  const int lane = threadIdx.x & 63;
  const size_t base = (size_t)row * DMODEL + lane * 8;
  uint4 ra = *(const uint4*)(pa + base);
  uint4 rb = *(const uint4*)(pb + base);
  uint4 rh = *(const uint4*)(hb + base);
  unsigned aa[4] = {ra.x, ra.y, ra.z, ra.w};
  unsigned ab[4] = {rb.x, rb.y, rb.z, rb.w};
  unsigned ah[4] = {rh.x, rh.y, rh.z, rh.w};
  float v[8];
#pragma unroll
  for (int k = 0; k < 4; ++k) {
    v[2 * k] = bf2f((ushort_t)(aa[k] & 0xffff)) +
               bf2f((ushort_t)(ab[k] & 0xffff)) +
               bf2f((ushort_t)(ah[k] & 0xffff));
    v[2 * k + 1] = bf2f((ushort_t)(aa[k] >> 16)) +
                   bf2f((ushort_t)(ab[k] >> 16)) +
                   bf2f((ushort_t)(ah[k] >> 16));
  }
  float sum = 0.f, sq = 0.f;
#pragma unroll
  for (int k = 0; k < 8; ++k) { sum += v[k]; sq += v[k] * v[k]; }
#pragma unroll
  for (int off = 32; off; off >>= 1) {
    sum += __shfl_xor(sum, off);
    sq += __shfl_xor(sq, off);
  }
  float mean = sum * (1.f / 512.f);
  float var = fmaxf(sq * (1.f / 512.f) - mean * mean, 0.f);
  float rstd = 1.f / sqrtf(var + 1e-5f);
  float4 g0 = *(const float4*)(g + lane * 8);
  float4 g1 = *(const float4*)(g + lane * 8 + 4);
  float4 c0 = *(const float4*)(bb + lane * 8);
  float4 c1 = *(const float4*)(bb + lane * 8 + 4);
  float gg[8] = {g0.x, g0.y, g0.z, g0.w, g1.x, g1.y, g1.z, g1.w};
  float cc[8] = {c0.x, c0.y, c0.z, c0.w, c1.x, c1.y, c1.z, c1.w};
  uint4 out;
  unsigned* op = (unsigned*)&out;
#pragma unroll
  for (int k = 0; k < 4; ++k) {
    float y0 = (v[2 * k] - mean) * rstd * gg[2 * k] + cc[2 * k];
    float y1 = (v[2 * k + 1] - mean) * rstd * gg[2 * k + 1] + cc[2 * k + 1];
    op[k] = (unsigned)f2bf(y0) | ((unsigned)f2bf(y1) << 16);
  }
  *(uint4*)(hb + base) = out;
}

// ---------------------------------------------------------------------------
// ProbSparse attention v14: v13 (prefix-scan compaction, coalesced 4-slot
// PV) + s_setprio(1) around the phase-1 MFMA cluster (T5, m191).
// ---------------------------------------------------------------------------
#define SST 1048

__global__ __launch_bounds__(512, 8) void attn_kernel(
    const ushort_t* __restrict__ Qb, const ushort_t* __restrict__ Kb,
    const ushort_t* __restrict__ Vb, ushort_t* __restrict__ Ob) {
  __shared__ _Float16 s16[16 * SST];
  __shared__ unsigned plist[16][64];

  const int tid = threadIdx.x;
  // XCD swizzle: grid (64, 8, 4) -> each XCD owns 4 (b,h) pairs x 64 q-tiles
  const int id = blockIdx.x + 64 * (blockIdx.y + 8 * blockIdx.z);
  const int xcd = id & 7;
  const int loc = id >> 3;
  const int bh = xcd * 4 + (loc & 3);
  const int q0 = (loc >> 2) * 16;
  const int b = bh >> 3;
  const int h = bh & 7;

  const int w = tid >> 6;
  const int lane = tid & 63;
  const int quad = lane >> 4, r16 = lane & 15;

  // ---- Phase 1: MFMA scores (16 queries x 128 keys per wave) ----
  {
    const int j0 = w * 128;
    const ushort_t* qrow =
        Qb + (size_t)(b * SEQ + q0 + r16) * DMODEL + h * DK + quad * 8;
    short8 aq0 = *(const short8*)qrow;
    short8 aq1 = *(const short8*)(qrow + 32);

    __builtin_amdgcn_s_setprio(1);
#pragma unroll
    for (int nt = 0; nt < 8; ++nt) {
      const ushort_t* krow =
          Kb + (size_t)(b * SEQ + j0 + nt * 16 + r16) * DMODEL + h * DK +
          quad * 8;
      short8 bk0 = *(const short8*)krow;
      short8 bk1 = *(const short8*)(krow + 32);
      float4v a = (float4v){0.f, 0.f, 0.f, 0.f};
      a = __builtin_amdgcn_mfma_f32_16x16x32_bf16(aq0, bk0, a, 0, 0, 0);
      a = __builtin_amdgcn_mfma_f32_16x16x32_bf16(aq1, bk1, a, 0, 0, 0);
#pragma unroll
      for (int reg = 0; reg < 4; ++reg)
        s16[(quad * 4 + reg) * SST + j0 + nt * 16 + r16] =
            (_Float16)(a[reg] * 0.125f);
    }
    __builtin_amdgcn_s_setprio(0);
  }
  __syncthreads();

  // ---- Phase 2: two queries per wave, scores register-cached ----
  {
    const int qa = w, qb2 = w + 8;
    const _Float16* sa = &s16[qa * SST];
    const _Float16* sb = &s16[qb2 * SST];
    const unsigned* sa32 = (const unsigned*)sa;
    const unsigned* sb32 = (const unsigned*)sb;

    // load all scores once: 8 packed u32 per query
    unsigned pk_a[8], pk_b[8];
#pragma unroll
    for (int i = 0; i < 8; ++i) {
      pk_a[i] = sa32[lane + 64 * i];
      pk_b[i] = sb32[lane + 64 * i];
    }

    // packed lane maxima (fp16)
    unsigned ma4 = pk_a[0], mb4 = pk_b[0];
#pragma unroll
    for (int i = 1; i < 8; ++i) {
      ma4 = pkmax(ma4, pk_a[i]);
      mb4 = pkmax(mb4, pk_b[i]);
    }
    ma4 = pkmax(ma4, ma4 >> 16);  // lo half = lane max of query a
    mb4 = pkmax(mb4, mb4 >> 16);
    const unsigned lm = (ma4 & 0xffffu) | (mb4 << 16);

    // wave max via packed shuffle reduce (both queries in one chain)
    unsigned mxp = lm;
#pragma unroll
    for (int j = 1; j <= 32; j <<= 1)
      mxp = pkmax(mxp, (unsigned)__shfl_xor((int)mxp, j));
    const float mxa = (float)u2h16((unsigned short)(mxp & 0xffffu));
    const float mxb = (float)u2h16((unsigned short)(mxp >> 16));

    // exact 34th-largest lane-max via ballot bisection on 16-bit keys
    const unsigned keyA = okey16(lm & 0xffffu);
    const unsigned keyB = okey16(lm >> 16);
    unsigned ansA = 0u, ansB = 0u;
#pragma unroll
    for (int bit = 15; bit >= 0; --bit) {
      const unsigned cA = ansA | (1u << bit);
      const unsigned cB = ansB | (1u << bit);
      const int cntA = (int)__popcll(__ballot(keyA >= cA));
      const int cntB = (int)__popcll(__ballot(keyB >= cB));
      if (cntA >= U_TOP) ansA = cA;
      if (cntB >= U_TOP) ansB = cB;
    }
    const _Float16 hTa = u2h16(ikey16(ansA));
    const _Float16 hTb = u2h16(ikey16(ansB));

    // ---- compaction: per-lane keep masks + one packed prefix scan ----
    unsigned maskA = 0u, maskB = 0u;
#pragma unroll
    for (int i = 0; i < 8; ++i) {
      const unsigned pa = pk_a[i], pb = pk_b[i];
      if (u2h16((unsigned short)pa) >= hTa) maskA |= (1u << (2 * i));
      if (u2h16((unsigned short)(pa >> 16)) >= hTa) maskA |= (2u << (2 * i));
      if (u2h16((unsigned short)pb) >= hTb) maskB |= (1u << (2 * i));
      if (u2h16((unsigned short)(pb >> 16)) >= hTb) maskB |= (2u << (2 * i));
    }
    const unsigned cntpk =
        (unsigned)__popc(maskA) | ((unsigned)__popc(maskB) << 16);
    unsigned scan = cntpk;
#pragma unroll
    for (int d = 1; d < 64; d <<= 1) {
      unsigned y = (unsigned)__shfl_up((int)scan, d);
      if (lane >= d) scan += y;
    }
    const unsigned pre = scan - cntpk;
    const unsigned tot = (unsigned)__shfl((int)scan, 63);
    int ca = (int)(tot & 0xffffu), cb = (int)(tot >> 16);
    int pA = (int)(pre & 0xffffu), pB = (int)(pre >> 16);
#pragma unroll
    for (int i = 0; i < 8; ++i) {
      const unsigned pa = pk_a[i], pb = pk_b[i];
      const int jb = 2 * lane + 128 * i;
      if (maskA & (1u << (2 * i))) {
        if (pA < 64) plist[qa][pA] = ((unsigned)jb << 16) | (pa & 0xffffu);
        ++pA;
      }
      if (maskA & (2u << (2 * i))) {
        if (pA < 64) plist[qa][pA] = ((unsigned)(jb + 1) << 16) | (pa >> 16);
        ++pA;
      }
      if (maskB & (1u << (2 * i))) {
        if (pB < 64) plist[qb2][pB] = ((unsigned)jb << 16) | (pb & 0xffffu);
        ++pB;
      }
      if (maskB & (2u << (2 * i))) {
        if (pB < 64) plist[qb2][pB] = ((unsigned)(jb + 1) << 16) | (pb >> 16);
        ++pB;
      }
    }

    // rare fallback: >64 candidates -> bisection to tighter threshold
    if (__builtin_expect(ca > 64, 0)) {
      unsigned ans = 0u;
      int cge = ca;
      bool ex = false;
      for (int bit = 31; bit >= 0 && cge > 64 && !ex; --bit) {
        unsigned cand = ans | (1u << bit);
        float fc = keyinv(cand);
        int c = 0;
#pragma unroll
        for (int i = 0; i < 16; ++i)
          c += (int)__popcll(__ballot((float)sa[lane + 64 * i] >= fc));
        if (c >= U_TOP) { ans = cand; cge = c; ex = (c == U_TOP); }
      }
      float fa2 = keyinv(ans);
      int cc = 0;
#pragma unroll
      for (int i = 0; i < 16; ++i) {
        float va = (float)sa[lane + 64 * i];
        bool ka = va >= fa2;
        unsigned long long ma = __ballot(ka);
        if (ka) {
          int p = cc + mbcnt64(ma);
          if (p < 64)
            plist[qa][p] = ((unsigned)(lane + 64 * i) << 16) | h2u(va);
        }
        cc += (int)__popcll(ma);
      }
      ca = cc;
    }
    if (__builtin_expect(cb > 64, 0)) {
      unsigned ans = 0u;
      int cge = cb;
      bool ex = false;
      for (int bit = 31; bit >= 0 && cge > 64 && !ex; --bit) {
        unsigned cand = ans | (1u << bit);
        float fc = keyinv(cand);
        int c = 0;
#pragma unroll
        for (int i = 0; i < 16; ++i)
          c += (int)__popcll(__ballot((float)sb[lane + 64 * i] >= fc));
        if (c >= U_TOP) { ans = cand; cge = c; ex = (c == U_TOP); }
      }
      float fb2 = keyinv(ans);
      int cc = 0;
#pragma unroll
      for (int i = 0; i < 16; ++i) {
        float vb = (float)sb[lane + 64 * i];
        bool kb = vb >= fb2;
        unsigned long long mb = __ballot(kb);
        if (kb) {
          int p = cc + mbcnt64(mb);
          if (p < 64)
            plist[qb2][p] = ((unsigned)(lane + 64 * i) << 16) | h2u(vb);
        }
        cc += (int)__popcll(mb);
      }
      cb = cc;
    }
    ca = ca > 64 ? 64 : ca;
    cb = cb > 64 ? 64 : cb;

    // one candidate per lane; bisection over candidate keys -> exact 34th
    const unsigned pua = (lane < ca) ? plist[qa][lane] : 0u;
    const unsigned pub = (lane < cb) ? plist[qb2][lane] : 0u;
    const unsigned k2a = (lane < ca) ? okey16(pua & 0xffffu) : 0u;
    const unsigned k2b = (lane < cb) ? okey16(pub & 0xffffu) : 0u;
    unsigned an2A = 0u, an2B = 0u;
#pragma unroll
    for (int bit = 15; bit >= 0; --bit) {
      const unsigned cA = an2A | (1u << bit);
      const unsigned cB = an2B | (1u << bit);
      const int cntA = (int)__popcll(__ballot(k2a >= cA));
      const int cntB = (int)__popcll(__ballot(k2b >= cB));
      if (cntA >= U_TOP) an2A = cA;
      if (cntB >= U_TOP) an2B = cB;
    }
    const _Float16 tha = u2h16(ikey16(an2A));
    const _Float16 thb = u2h16(ikey16(an2B));

    // final keep set; exp only now
    const bool keepa = (lane < ca) && (u2h16((unsigned short)pua) >= tha);
    const bool keepb = (lane < cb) && (u2h16((unsigned short)pub) >= thb);
    unsigned long long kma = __ballot(keepa);
    unsigned long long kmb = __ballot(keepb);
    const int na = (int)__popcll(kma), nb = (int)__popcll(kmb);
    float ea = keepa ? __expf((float)u2h16((unsigned short)pua) - mxa) : 0.f;
    float eb = keepb ? __expf((float)u2h16((unsigned short)pub) - mxb) : 0.f;
    float za = ea, zb = eb;
#pragma unroll
    for (int off = 32; off; off >>= 1) {
      za += __shfl_xor(za, off);
      zb += __shfl_xor(zb, off);
    }
    if (keepa) plist[qa][mbcnt64(kma)] = (pua & 0xffff0000u) | h2u(ea);
    if (keepb) plist[qb2][mbcnt64(kmb)] = (pub & 0xffff0000u) | h2u(eb);

    // ---- sparse PV: 4 entry-slots x 16 dim-groups, dwordx2 loads ----
    const ushort_t* vbase = Vb + (size_t)b * SEQ * DMODEL + h * DK;
    const int slot = lane >> 4;   // 0..3: which entry within a 4-block
    const int dgrp = lane & 15;   // dims [4*dgrp, 4*dgrp+4)
    const int d4 = dgrp * 4;
    float aA0 = 0.f, aA1 = 0.f, aA2 = 0.f, aA3 = 0.f;
    float aB0 = 0.f, aB1 = 0.f, aB2 = 0.f, aB3 = 0.f;
    const int nmax = na > nb ? na : nb;
    for (int i = slot; i < nmax; i += 4) {
      const unsigned ua = (i < na) ? plist[qa][i] : 0u;   // weight 0 if OOB
      const unsigned ub = (i < nb) ? plist[qb2][i] : 0u;
      const uint2 va =
          *(const uint2*)(vbase + (size_t)(ua >> 16) * DMODEL + d4);
      const uint2 vb =
          *(const uint2*)(vbase + (size_t)(ub >> 16) * DMODEL + d4);
      const float wa = (float)u2h16((unsigned short)ua);
      const float wb = (float)u2h16((unsigned short)ub);
      aA0 += wa * __uint_as_float(va.x << 16);
      aA1 += wa * __uint_as_float(va.x & 0xffff0000u);
      aA2 += wa * __uint_as_float(va.y << 16);
      aA3 += wa * __uint_as_float(va.y & 0xffff0000u);
      aB0 += wb * __uint_as_float(vb.x << 16);
      aB1 += wb * __uint_as_float(vb.x & 0xffff0000u);
      aB2 += wb * __uint_as_float(vb.y << 16);
      aB3 += wb * __uint_as_float(vb.y & 0xffff0000u);
    }
    // reduce over the 4 entry-slots (lanes g, g+16, g+32, g+48)
    aA0 += __shfl_xor(aA0, 16); aA0 += __shfl_xor(aA0, 32);
    aA1 += __shfl_xor(aA1, 16); aA1 += __shfl_xor(aA1, 32);
    aA2 += __shfl_xor(aA2, 16); aA2 += __shfl_xor(aA2, 32);
    aA3 += __shfl_xor(aA3, 16); aA3 += __shfl_xor(aA3, 32);
    aB0 += __shfl_xor(aB0, 16); aB0 += __shfl_xor(aB0, 32);
    aB1 += __shfl_xor(aB1, 16); aB1 += __shfl_xor(aB1, 32);
    aB2 += __shfl_xor(aB2, 16); aB2 += __shfl_xor(aB2, 32);
    aB3 += __shfl_xor(aB3, 16); aB3 += __shfl_xor(aB3, 32);

    const float iza = 1.f / za, izb = 1.f / zb;
    if (slot == 0) {
      uint2 o;
      o.x = (unsigned)f2bf(aA0 * iza) | ((unsigned)f2bf(aA1 * iza) << 16);
      o.y = (unsigned)f2bf(aA2 * iza) | ((unsigned)f2bf(aA3 * iza) << 16);
      *(uint2*)(Ob + (size_t)(b * SEQ + q0 + qa) * DMODEL + h * DK + d4) = o;
    } else if (slot == 1) {
      uint2 o;
      o.x = (unsigned)f2bf(aB0 * izb) | ((unsigned)f2bf(aB1 * izb) << 16);
      o.y = (unsigned)f2bf(aB2 * izb) | ((unsigned)f2bf(aB3 * izb) << 16);
      *(uint2*)(Ob + (size_t)(b * SEQ + q0 + qb2) * DMODEL + h * DK + d4) = o;
    }
  }
}

// ---------------------------------------------------------------------------
// Orchestration (R9 best config).  ws layout (MiB): ffh/qkv [0,16) (Wo
// partials reuse [0,8) after attn) | ao [16,20) (xb pre-loop; FFN2 partials
// reuse [16,24)) | [20,24) FFN2 partial 1 | hb [24,28) | wt [28, 46.2).
// Layer GEMMs: BK=64 2-phase dbuf. FFN1 BN=128 (512 blk); QKV BN=64
// (768 blk); Wo/FFN2 split-K BN=64 (512 blk each).
// ---------------------------------------------------------------------------
extern "C" void kernel_launch(void* const* d_in, const int* in_sizes, int n_in,
                              void* d_out, int out_size, void* d_ws,
                              size_t ws_size, hipStream_t stream) {
  const float* x = (const float*)d_in[0];
  const float* W_emb = (const float*)d_in[1];
  const float* b_emb = (const float*)d_in[2];
  const float* Wq = (const float*)d_in[3];
  const float* bq = (const float*)d_in[4];
  const float* Wk = (const float*)d_in[5];
  const float* bk = (const float*)d_in[6];
  const float* Wv = (const float*)d_in[7];
  const float* bv = (const float*)d_in[8];
  const float* Wo = (const float*)d_in[9];
  const float* bo = (const float*)d_in[10];
  const float* ln1_g = (const float*)d_in[11];
  const float* ln1_b = (const float*)d_in[12];
  const float* W1 = (const float*)d_in[13];
  const float* b1 = (const float*)d_in[14];
  const float* W2 = (const float*)d_in[15];
  const float* b2 = (const float*)d_in[16];
  const float* ln2_g = (const float*)d_in[17];
  const float* ln2_b = (const float*)d_in[18];
  const float* W_dec = (const float*)d_in[19];
  const float* b_dec = (const float*)d_in[20];

  char* wsb = (char*)d_ws;
  ushort_t* qkv = (ushort_t*)wsb;
  ushort_t* ffh = (ushort_t*)wsb;
  ushort_t* wop = (ushort_t*)wsb;  // Wo partials [0,8M)
  ushort_t* ao = (ushort_t*)(wsb + ((size_t)16 << 20));
  ushort_t* xb = (ushort_t*)(wsb + ((size_t)16 << 20));
  ushort_t* ffp = (ushort_t*)(wsb + ((size_t)16 << 20));  // FFN2 partials
  ushort_t* hb = (ushort_t*)(wsb + ((size_t)24 << 20));
  short* wt = (short*)(wsb + ((size_t)28 << 20));
  short* wembT = wt + 9437184;
  short* wdecT = wt + 9502720;

  f32_to_bf16_kernel<<<dim3(512), 256, 0, stream>>>(x, xb);
  convert_all<<<dim3(9312), dim3(32, 8), 0, stream>>>(Wq, Wk, Wv, Wo, W1, W2,
                                                      W_emb, W_dec, wt);
  // embed: hb = bf16((xb @ W_emb + b_emb)*sqrt(512) + PE)
  gemm64<0, 1, 2, 0><<<dim3(8, 64), 256, 0, stream>>>(
      xb, wembT, b_emb, (void*)hb, nullptr, 128, 512);

  for (int i = 0; i < 3; ++i) {
    short* wtL = wt + (size_t)i * 3145728;

    // QKV: one N=1536 GEMM on 128x64 tiles (768 blocks, 3/CU)
    gemmT<0, 1, 64><<<dim3(24, 32), 256, 0, stream>>>(
        hb, wtL, bq + i * DMODEL, bk + i * DMODEL, bv + i * DMODEL, qkv, 512,
        512, 2097152);

    attn_kernel<<<dim3(SEQ / 16, NHEAD, BATCH), dim3(512), 0, stream>>>(
        qkv, qkv + 2097152, qkv + 4194304, ao);

    // Wo split-K (K=512 -> 2x256), 128x64 tiles (512 blocks, 2/CU)
    gemmskT<64><<<dim3(8, 32, 2), 256, 0, stream>>>(
        ao, wtL + 786432, bo + i * DMODEL, wop, 512, 256);
    ln_red_kernel<<<dim3(ROWS / 4), 256, 0, stream>>>(
        wop, wop + 2097152, ln1_g + i * DMODEL, ln1_b + i * DMODEL, hb);

    // FFN1 N=2048 on 128x128 tiles (512 blocks, 2/CU, 250B staged/MFMA)
    gemmT<1, 0, 128><<<dim3(16, 32), 256, 0, stream>>>(
        hb, wtL + 1048576, b1 + i * DFF, nullptr, nullptr, ffh, 512, 2048, 0);
    // FFN2 split-K (K=2048 -> 2x1024), 128x64 tiles (512 blocks, 2/CU)
    gemmskT<64><<<dim3(8, 32, 2), 256, 0, stream>>>(
        ffh, wtL + 2097152, b2 + i * DMODEL, ffp, 2048, 1024);
    ln_red_kernel<<<dim3(ROWS / 4), 256, 0, stream>>>(
        ffp, ffp + 2097152, ln2_g + i * DMODEL, ln2_b + i * DMODEL, hb);
  }

  gemm64<0, 0, 0, 0><<<dim3(1, 64), 256, 0, stream>>>(
      hb, wdecT, b_dec, d_out, nullptr, 512, 64);
}

// Round 13
// 487.991 us; speedup vs baseline: 1.0273x; 1.0273x over previous
//
#include <hip/hip_runtime.h>
#include <math.h>

#define SEQ 1024
#define BATCH 4
#define DMODEL 512
#define NHEAD 8
#define DK 64
#define DFF 2048
#define U_TOP 34
#define ROWS (BATCH * SEQ)

typedef unsigned short ushort_t;
typedef __attribute__((ext_vector_type(8))) short short8;
typedef __attribute__((ext_vector_type(4))) float float4v;
typedef __attribute__((ext_vector_type(2))) _Float16 h2v;

__device__ inline ushort_t f2bf(float f) {
  unsigned u = __float_as_uint(f);
  unsigned r = u + 0x7fffu + ((u >> 16) & 1u);
  return (ushort_t)(r >> 16);
}
__device__ inline float bf2f(ushort_t u) {
  return __uint_as_float((unsigned)u << 16);
}
// ordered-uint key -> float (rare >64-candidate fallback only)
__device__ inline float keyinv(unsigned cand) {
  unsigned fb = (cand & 0x80000000u) ? (cand ^ 0x80000000u) : ~cand;
  return __uint_as_float(fb);
}

union H16 { _Float16 h; unsigned short u; };
__device__ inline unsigned short h2u(float f) {
  H16 t; t.h = (_Float16)f; return t.u;
}
__device__ inline float u2h(unsigned short u) {
  H16 t; t.u = u; return (float)t.h;
}
__device__ inline _Float16 u2h16(unsigned short u) {
  H16 t; t.u = u; return t.h;
}
// fp16 bits -> 16-bit ordered key (unsigned compare == float compare)
__device__ inline unsigned okey16(unsigned b) {
  return (b ^ (0x8000u | ((b >> 15) * 0x7FFFu))) & 0xFFFFu;
}
// inverse of okey16
__device__ inline unsigned short ikey16(unsigned k) {
  return (unsigned short)(k ^ ((k >> 15) ? 0x8000u : 0xFFFFu));
}
__device__ inline int mbcnt64(unsigned long long m) {
  int lo = __builtin_amdgcn_mbcnt_lo((unsigned)m, 0);
  return __builtin_amdgcn_mbcnt_hi((unsigned)(m >> 32), lo);
}

__device__ inline void glds16(const void* g, void* l) {
  __builtin_amdgcn_global_load_lds(
      (const __attribute__((address_space(1))) unsigned int*)g,
      (__attribute__((address_space(3))) unsigned int*)l, 16, 0, 0);
}

// packed fp16 max (v_pk_max_f16)
__device__ inline unsigned pkmax(unsigned a, unsigned b) {
  return __builtin_bit_cast(unsigned, __builtin_elementwise_max(
      __builtin_bit_cast(h2v, a), __builtin_bit_cast(h2v, b)));
}

// ---------------------------------------------------------------------------
// bf16 MFMA GEMM, 128xBN tile (BN in {64,128}), BK=64 staged as TWO adjacent
// BK=32 sub-tiles, 2-phase double-buffered K-loop: stage(t+1) issued BEFORE
// the ds_read+MFMA of tile t; ONE barrier per 64-wide K-step.
// BN=64: 48KB LDS -> 3 blocks/CU (QKV). BN=128: 64KB -> 2 blocks/CU but
// 250B staged/MFMA (FFN1, N=2048).
// XCD swizzle: each XCD owns a band of row-tiles (A fetched once per band).
// SPLIT=1 (QKV): Bt has 1536 rows (Wq|Wk|Wv); z=bn>>9 routes output/bias.
// Requires gridDim.y % 8 == 0 and K % 64 == 0.
// ---------------------------------------------------------------------------
template <int RELU, int SPLIT, int BN>
__global__ __launch_bounds__(256) void gemmT(
    const ushort_t* __restrict__ A, const short* __restrict__ Bt,
    const float* __restrict__ b0, const float* __restrict__ b1,
    const float* __restrict__ b2, ushort_t* __restrict__ Cout,
    int K, int N, int zCstride) {
  constexpr int NT = BN / 32;  // n-tiles per wave (wave covers BN/2 cols)
  __shared__ short As[2][2][128 * 32];
  __shared__ short Bs[2][2][BN * 32];

  const int tid = threadIdx.x;
  const int lane = tid & 63, w = tid >> 6;
  const int wm = w >> 1, wn = w & 1;
  const int quad = lane >> 4, r16 = lane & 15;

  // XCD-affinity block swizzle (round-robin id%8 -> XCD heuristic)
  const int id = blockIdx.y * gridDim.x + blockIdx.x;
  const int xcd = id & 7;
  const int loc = id >> 3;
  const int rpx = gridDim.y >> 3;  // row-tiles per XCD
  const int bm = (xcd * rpx + (loc % rpx)) * 128;
  const int bn = (loc / rpx) * BN;

  const int srow = lane >> 2, skseg = lane & 3;
  const ushort_t* Ag0 = A + (size_t)(bm + w * 16 + srow) * K + skseg * 8;
  const ushort_t* Ag1 = Ag0 + (size_t)64 * K;
  const short* Bg0 = Bt + (size_t)(bn + w * 16 + srow) * K + skseg * 8;
  const short* Bg1 = Bg0 + (size_t)64 * K;
  const int aoff0 = (w * 16) * 32;
  const int aoff1 = (64 + w * 16) * 32;
  const int boff0 = (w * 16) * 32;
  const int boff1 = (64 + w * 16) * 32;

  float4v acc[4][NT];
#pragma unroll
  for (int m = 0; m < 4; ++m)
#pragma unroll
    for (int n = 0; n < NT; ++n) acc[m][n] = (float4v){0.f, 0.f, 0.f, 0.f};

  // stage one 64-wide K-tile (two 32-wide halves) into buffer bi
  auto stage = [&](int k0, int bi) {
#pragma unroll
    for (int hh = 0; hh < 2; ++hh) {
      glds16(Ag0 + k0 + hh * 32, &As[bi][hh][aoff0]);
      glds16(Ag1 + k0 + hh * 32, &As[bi][hh][aoff1]);
      glds16(Bg0 + k0 + hh * 32, &Bs[bi][hh][boff0]);
      if (BN == 128) glds16(Bg1 + k0 + hh * 32, &Bs[bi][hh][boff1]);
    }
  };

  stage(0, 0);
  __syncthreads();  // compiler emits vmcnt(0) before barrier

  int cur = 0;
  for (int k0 = 0; k0 < K; k0 += 64) {
    if (k0 + 64 < K) stage(k0 + 64, cur ^ 1);

#pragma unroll
    for (int hh = 0; hh < 2; ++hh) {
      short8 af[4], bfr[NT];
#pragma unroll
      for (int m = 0; m < 4; ++m)
        af[m] = *(const short8*)&As[cur][hh][(wm * 64 + m * 16 + r16) * 32 +
                                             quad * 8];
#pragma unroll
      for (int n = 0; n < NT; ++n)
        bfr[n] = *(const short8*)&Bs[cur][hh][(wn * (BN / 2) + n * 16 + r16) *
                                                  32 +
                                              quad * 8];
#pragma unroll
      for (int m = 0; m < 4; ++m)
#pragma unroll
        for (int n = 0; n < NT; ++n)
          acc[m][n] = __builtin_amdgcn_mfma_f32_16x16x32_bf16(
              af[m], bfr[n], acc[m][n], 0, 0, 0);
    }
    __syncthreads();  // drains new stage + ds_reads; 1 barrier per 64-K step
    cur ^= 1;
  }

  const int z = SPLIT ? (bn >> 9) : 0;
  const float* bias = (z == 0) ? b0 : (z == 1 ? b1 : b2);
  const int cbase = SPLIT ? (bn & 511) : bn;
  const int strideN = SPLIT ? 512 : N;
  ushort_t* C = Cout + (SPLIT ? (size_t)z * zCstride : (size_t)0);

  float bias_n[NT];
#pragma unroll
  for (int n = 0; n < NT; ++n)
    bias_n[n] = bias[cbase + wn * (BN / 2) + n * 16 + r16];

#pragma unroll
  for (int m = 0; m < 4; ++m) {
#pragma unroll
    for (int n = 0; n < NT; ++n) {
      int col = cbase + wn * (BN / 2) + n * 16 + r16;
#pragma unroll
      for (int reg = 0; reg < 4; ++reg) {
        int row = bm + wm * 64 + m * 16 + quad * 4 + reg;
        float v = acc[m][n][reg] + bias_n[n];
        if (RELU) v = fmaxf(v, 0.f);
        C[(size_t)row * strideN + col] = f2bf(v);
      }
    }
  }
}

// ---------------------------------------------------------------------------
// Split-K bf16 MFMA GEMM, 128xBN tile over K-range [z*Ks, (z+1)*Ks).
// Same BK=64 two-half 2-phase K-loop as gemmT. Requires Ks % 64 == 0.
// Writes bf16 partials to pout + z*2097152 (N fixed 512). Bias on z==0.
// ---------------------------------------------------------------------------
template <int BN>
__global__ __launch_bounds__(256) void gemmskT(
    const ushort_t* __restrict__ A, const short* __restrict__ Bt,
    const float* __restrict__ bias, ushort_t* __restrict__ pout,
    int K, int Ks) {
  constexpr int NT = BN / 32;
  __shared__ short As[2][2][128 * 32];
  __shared__ short Bs[2][2][BN * 32];

  const int tid = threadIdx.x;
  const int lane = tid & 63, w = tid >> 6;
  const int wm = w >> 1, wn = w & 1;
  const int quad = lane >> 4, r16 = lane & 15;

  const int id = blockIdx.y * gridDim.x + blockIdx.x;
  const int xcd = id & 7;
  const int loc = id >> 3;
  const int rpx = gridDim.y >> 3;
  const int bm = (xcd * rpx + (loc % rpx)) * 128;
  const int bn = (loc / rpx) * BN;
  const int z = blockIdx.z;
  const int koff = z * Ks;

  const int srow = lane >> 2, skseg = lane & 3;
  const ushort_t* Ag0 =
      A + (size_t)(bm + w * 16 + srow) * K + skseg * 8 + koff;
  const ushort_t* Ag1 = Ag0 + (size_t)64 * K;
  const short* Bg0 = Bt + (size_t)(bn + w * 16 + srow) * K + skseg * 8 + koff;
  const short* Bg1 = Bg0 + (size_t)64 * K;
  const int aoff0 = (w * 16) * 32;
  const int aoff1 = (64 + w * 16) * 32;
  const int boff0 = (w * 16) * 32;
  const int boff1 = (64 + w * 16) * 32;

  float4v acc[4][NT];
#pragma unroll
  for (int m = 0; m < 4; ++m)
#pragma unroll
    for (int n = 0; n < NT; ++n) acc[m][n] = (float4v){0.f, 0.f, 0.f, 0.f};

  auto stage = [&](int k0, int bi) {
#pragma unroll
    for (int hh = 0; hh < 2; ++hh) {
      glds16(Ag0 + k0 + hh * 32, &As[bi][hh][aoff0]);
      glds16(Ag1 + k0 + hh * 32, &As[bi][hh][aoff1]);
      glds16(Bg0 + k0 + hh * 32, &Bs[bi][hh][boff0]);
      if (BN == 128) glds16(Bg1 + k0 + hh * 32, &Bs[bi][hh][boff1]);
    }
  };

  stage(0, 0);
  __syncthreads();

  int cur = 0;
  for (int k0 = 0; k0 < Ks; k0 += 64) {
    if (k0 + 64 < Ks) stage(k0 + 64, cur ^ 1);

#pragma unroll
    for (int hh = 0; hh < 2; ++hh) {
      short8 af[4], bfr[NT];
#pragma unroll
      for (int m = 0; m < 4; ++m)
        af[m] = *(const short8*)&As[cur][hh][(wm * 64 + m * 16 + r16) * 32 +
                                             quad * 8];
#pragma unroll
      for (int n = 0; n < NT; ++n)
        bfr[n] = *(const short8*)&Bs[cur][hh][(wn * (BN / 2) + n * 16 + r16) *
                                                  32 +
                                              quad * 8];
#pragma unroll
      for (int m = 0; m < 4; ++m)
#pragma unroll
        for (int n = 0; n < NT; ++n)
          acc[m][n] = __builtin_amdgcn_mfma_f32_16x16x32_bf16(
              af[m], bfr[n], acc[m][n], 0, 0, 0);
    }
    __syncthreads();
    cur ^= 1;
  }

  ushort_t* P = pout + (size_t)z * 2097152;
  float bias_n[NT];
#pragma unroll
  for (int n = 0; n < NT; ++n)
    bias_n[n] = (z == 0) ? bias[bn + wn * (BN / 2) + n * 16 + r16] : 0.f;

#pragma unroll
  for (int m = 0; m < 4; ++m) {
#pragma unroll
    for (int n = 0; n < NT; ++n) {
      int col = bn + wn * (BN / 2) + n * 16 + r16;
#pragma unroll
      for (int reg = 0; reg < 4; ++reg) {
        int row = bm + wm * 64 + m * 16 + quad * 4 + reg;
        float v = acc[m][n][reg] + bias_n[n];
        P[(size_t)row * 512 + col] = f2bf(v);
      }
    }
  }
}

// ---------------------------------------------------------------------------
// bf16 MFMA GEMM, tile 64x64 (embed + decode only), BK=64 two-half 2-phase.
// EPI 0: none. EPI 2: v = v*sqrt(512) + positional encoding (embed).
// Requires K % 64 == 0 (embed K=128, decode K=512).
// ---------------------------------------------------------------------------
template <int RELU, int OUTBF16, int EPI, int ADDC>
__global__ __launch_bounds__(256) void gemm64(
    const ushort_t* __restrict__ A, const short* __restrict__ Bt,
    const float* __restrict__ bias, void* __restrict__ Cout,
    const ushort_t* __restrict__ Cadd, int K, int N) {
  __shared__ short As[2][2][64 * 32];
  __shared__ short Bs[2][2][64 * 32];

  const int tid = threadIdx.x;
  const int lane = tid & 63, w = tid >> 6;
  const int wm = w >> 1, wn = w & 1;
  const int quad = lane >> 4, r16 = lane & 15;
  const int bm = blockIdx.y * 64, bn = blockIdx.x * 64;

  const int srow = tid >> 2, skseg = tid & 3;
  const ushort_t* Ag = A + (size_t)(bm + srow) * K + skseg * 8;
  const short* Bg = Bt + (size_t)(bn + srow) * K + skseg * 8;
  const int loff = w * 512;

  float4v acc[2][2];
#pragma unroll
  for (int m = 0; m < 2; ++m)
#pragma unroll
    for (int n = 0; n < 2; ++n) acc[m][n] = (float4v){0.f, 0.f, 0.f, 0.f};

  auto stage = [&](int k0, int bi) {
#pragma unroll
    for (int hh = 0; hh < 2; ++hh) {
      glds16(Ag + k0 + hh * 32, &As[bi][hh][loff]);
      glds16(Bg + k0 + hh * 32, &Bs[bi][hh][loff]);
    }
  };

  stage(0, 0);
  __syncthreads();

  int cur = 0;
  for (int k0 = 0; k0 < K; k0 += 64) {
    if (k0 + 64 < K) stage(k0 + 64, cur ^ 1);

#pragma unroll
    for (int hh = 0; hh < 2; ++hh) {
      short8 af[2], bfr[2];
#pragma unroll
      for (int m = 0; m < 2; ++m)
        af[m] = *(const short8*)&As[cur][hh][(wm * 32 + m * 16 + r16) * 32 +
                                             quad * 8];
#pragma unroll
      for (int n = 0; n < 2; ++n)
        bfr[n] = *(const short8*)&Bs[cur][hh][(wn * 32 + n * 16 + r16) * 32 +
                                              quad * 8];
#pragma unroll
      for (int m = 0; m < 2; ++m)
#pragma unroll
        for (int n = 0; n < 2; ++n)
          acc[m][n] = __builtin_amdgcn_mfma_f32_16x16x32_bf16(
              af[m], bfr[n], acc[m][n], 0, 0, 0);
    }
    __syncthreads();
    cur ^= 1;
  }

  const float pe_c = (float)(-9.210340371976184 / 512.0);
  const float sqrtd = 22.62741699796952f;

  float bias_n[2];
#pragma unroll
  for (int n = 0; n < 2; ++n) bias_n[n] = bias[bn + wn * 32 + n * 16 + r16];

#pragma unroll
  for (int m = 0; m < 2; ++m) {
#pragma unroll
    for (int n = 0; n < 2; ++n) {
      int col = bn + wn * 32 + n * 16 + r16;
#pragma unroll
      for (int reg = 0; reg < 4; ++reg) {
        int row = bm + wm * 32 + m * 16 + quad * 4 + reg;
        float v = acc[m][n][reg] + bias_n[n];
        if (RELU) v = fmaxf(v, 0.f);
        if (EPI == 2) {
          int pos = row & (SEQ - 1);
          float e = __expf((float)(col & ~1) * pe_c);
          float arg = (float)pos * e;
          v = v * sqrtd + ((col & 1) ? __cosf(arg) : __sinf(arg));
        }
        if (ADDC) v += bf2f(Cadd[(size_t)row * N + col]);
        if (OUTBF16) {
          ((ushort_t*)Cout)[(size_t)row * N + col] = f2bf(v);
        } else {
          ((float*)Cout)[(size_t)row * N + col] = v;
        }
      }
    }
  }
}

// ---------------------------------------------------------------------------
// All weights (3 layers + emb + dec): W[K][N] f32 -> Wt[N][K] bf16, 1 launch.
// ---------------------------------------------------------------------------
__global__ __launch_bounds__(256) void convert_all(
    const float* __restrict__ Wq, const float* __restrict__ Wk,
    const float* __restrict__ Wv, const float* __restrict__ Wo,
    const float* __restrict__ W1, const float* __restrict__ W2,
    const float* __restrict__ W_emb, const float* __restrict__ W_dec,
    short* __restrict__ wt) {
  __shared__ float t[32][33];
  int id = blockIdx.x;
  const float* src;
  short* dst;
  int K, N, tk, tn;
  if (id < 9216) {
    int lay = id / 3072, r = id % 3072;
    short* wl = wt + (size_t)lay * 3145728;
    const size_t wsz = 512 * 512;
    if (r < 1024) {
      int wi = r >> 8, tile = r & 255;
      const float* base = (wi == 0) ? Wq : (wi == 1) ? Wk : (wi == 2) ? Wv : Wo;
      src = base + lay * wsz;
      dst = wl + wi * 262144;
      K = 512; N = 512; tk = tile >> 4; tn = tile & 15;
    } else if (r < 2048) {
      int tile = r - 1024;
      src = W1 + (size_t)lay * 512 * 2048;
      dst = wl + 1048576;
      K = 512; N = 2048; tk = tile >> 6; tn = tile & 63;
    } else {
      int tile = r - 2048;
      src = W2 + (size_t)lay * 2048 * 512;
      dst = wl + 2097152;
      K = 2048; N = 512; tk = tile >> 4; tn = tile & 15;
    }
  } else {
    int r = id - 9216;
    if (r < 64) {
      src = W_emb; dst = wt + 9437184; K = 128; N = 512; tk = r >> 4; tn = r & 15;
    } else {
      r -= 64;
      src = W_dec; dst = wt + 9502720; K = 512; N = 64; tk = r >> 1; tn = r & 1;
    }
  }
  const int k0 = tk * 32, n0 = tn * 32;
  const int tx = threadIdx.x, ty = threadIdx.y;
#pragma unroll
  for (int i = 0; i < 4; ++i) {
    int r = ty + i * 8;
    t[r][tx] = src[(size_t)(k0 + r) * N + n0 + tx];
  }
  __syncthreads();
#pragma unroll
  for (int i = 0; i < 4; ++i) {
    int r = ty + i * 8;
    dst[(size_t)(n0 + r) * K + k0 + tx] = (short)f2bf(t[tx][r]);
  }
}

__global__ __launch_bounds__(256) void f32_to_bf16_kernel(
    const float* __restrict__ src, ushort_t* __restrict__ dst) {
  int i = blockIdx.x * blockDim.x + threadIdx.x;
  float4 v = ((const float4*)src)[i];
  ushort4 o;
  o.x = f2bf(v.x); o.y = f2bf(v.y); o.z = f2bf(v.z); o.w = f2bf(v.w);
  ((ushort4*)dst)[i] = o;
}

// ---------------------------------------------------------------------------
// Split-K reduce + residual + LayerNorm: hb = LN(pa + pb + hb) * g + b.
// ---------------------------------------------------------------------------
__global__ __launch_bounds__(256) void ln_red_kernel(
    const ushort_t* __restrict__ pa, const ushort_t* __restrict__ pb,
    const float* __restrict__ g, const float* __restrict__ bb,
    ushort_t* __restrict__ hb) {
  const int row = blockIdx.x * 4 + (threadIdx.x >> 6);
  const int lane = threadIdx.x & 63;
  const size_t base = (size_t)row * DMODEL + lane * 8;
  uint4 ra = *(const uint4*)(pa + base);
  uint4 rb = *(const uint4*)(pb + base);
  uint4 rh = *(const uint4*)(hb + base);
  unsigned aa[4] = {ra.x, ra.y, ra.z, ra.w};
  unsigned ab[4] = {rb.x, rb.y, rb.z, rb.w};
  unsigned ah[4] = {rh.x, rh.y, rh.z, rh.w};
  float v[8];
#pragma unroll
  for (int k = 0; k < 4; ++k) {
    v[2 * k] = bf2f((ushort_t)(aa[k] & 0xffff)) +
               bf2f((ushort_t)(ab[k] & 0xffff)) +
               bf2f((ushort_t)(ah[k] & 0xffff));
    v[2 * k + 1] = bf2f((ushort_t)(aa[k] >> 16)) +
                   bf2f((ushort_t)(ab[k] >> 16)) +
                   bf2f((ushort_t)(ah[k] >> 16));
  }
  float sum = 0.f, sq = 0.f;
#pragma unroll
  for (int k = 0; k < 8; ++k) { sum += v[k]; sq += v[k] * v[k]; }
#pragma unroll
  for (int off = 32; off; off >>= 1) {
    sum += __shfl_xor(sum, off);
    sq += __shfl_xor(sq, off);
  }
  float mean = sum * (1.f / 512.f);
  float var = fmaxf(sq * (1.f / 512.f) - mean * mean, 0.f);
  float rstd = 1.f / sqrtf(var + 1e-5f);
  float4 g0 = *(const float4*)(g + lane * 8);
  float4 g1 = *(const float4*)(g + lane * 8 + 4);
  float4 c0 = *(const float4*)(bb + lane * 8);
  float4 c1 = *(const float4*)(bb + lane * 8 + 4);
  float gg[8] = {g0.x, g0.y, g0.z, g0.w, g1.x, g1.y, g1.z, g1.w};
  float cc[8] = {c0.x, c0.y, c0.z, c0.w, c1.x, c1.y, c1.z, c1.w};
  uint4 out;
  unsigned* op = (unsigned*)&out;
#pragma unroll
  for (int k = 0; k < 4; ++k) {
    float y0 = (v[2 * k] - mean) * rstd * gg[2 * k] + cc[2 * k];
    float y1 = (v[2 * k + 1] - mean) * rstd * gg[2 * k + 1] + cc[2 * k + 1];
    op[k] = (unsigned)f2bf(y0) | ((unsigned)f2bf(y1) << 16);
  }
  *(uint4*)(hb + base) = out;
}

// ---------------------------------------------------------------------------
// ProbSparse attention v13 (verified best: prefix-scan compaction, coalesced
// 4-slot PV; setprio reverted -- R12 showed it costs ~5us at this occupancy).
// ---------------------------------------------------------------------------
#define SST 1048

__global__ __launch_bounds__(512, 8) void attn_kernel(
    const ushort_t* __restrict__ Qb, const ushort_t* __restrict__ Kb,
    const ushort_t* __restrict__ Vb, ushort_t* __restrict__ Ob) {
  __shared__ _Float16 s16[16 * SST];
  __shared__ unsigned plist[16][64];

  const int tid = threadIdx.x;
  // XCD swizzle: grid (64, 8, 4) -> each XCD owns 4 (b,h) pairs x 64 q-tiles
  const int id = blockIdx.x + 64 * (blockIdx.y + 8 * blockIdx.z);
  const int xcd = id & 7;
  const int loc = id >> 3;
  const int bh = xcd * 4 + (loc & 3);
  const int q0 = (loc >> 2) * 16;
  const int b = bh >> 3;
  const int h = bh & 7;

  const int w = tid >> 6;
  const int lane = tid & 63;
  const int quad = lane >> 4, r16 = lane & 15;

  // ---- Phase 1: MFMA scores (16 queries x 128 keys per wave) ----
  {
    const int j0 = w * 128;
    const ushort_t* qrow =
        Qb + (size_t)(b * SEQ + q0 + r16) * DMODEL + h * DK + quad * 8;
    short8 aq0 = *(const short8*)qrow;
    short8 aq1 = *(const short8*)(qrow + 32);

#pragma unroll
    for (int nt = 0; nt < 8; ++nt) {
      const ushort_t* krow =
          Kb + (size_t)(b * SEQ + j0 + nt * 16 + r16) * DMODEL + h * DK +
          quad * 8;
      short8 bk0 = *(const short8*)krow;
      short8 bk1 = *(const short8*)(krow + 32);
      float4v a = (float4v){0.f, 0.f, 0.f, 0.f};
      a = __builtin_amdgcn_mfma_f32_16x16x32_bf16(aq0, bk0, a, 0, 0, 0);
      a = __builtin_amdgcn_mfma_f32_16x16x32_bf16(aq1, bk1, a, 0, 0, 0);
#pragma unroll
      for (int reg = 0; reg < 4; ++reg)
        s16[(quad * 4 + reg) * SST + j0 + nt * 16 + r16] =
            (_Float16)(a[reg] * 0.125f);
    }
  }
  __syncthreads();

  // ---- Phase 2: two queries per wave, scores register-cached ----
  {
    const int qa = w, qb2 = w + 8;
    const _Float16* sa = &s16[qa * SST];
    const _Float16* sb = &s16[qb2 * SST];
    const unsigned* sa32 = (const unsigned*)sa;
    const unsigned* sb32 = (const unsigned*)sb;

    // load all scores once: 8 packed u32 per query
    unsigned pk_a[8], pk_b[8];
#pragma unroll
    for (int i = 0; i < 8; ++i) {
      pk_a[i] = sa32[lane + 64 * i];
      pk_b[i] = sb32[lane + 64 * i];
    }

    // packed lane maxima (fp16)
    unsigned ma4 = pk_a[0], mb4 = pk_b[0];
#pragma unroll
    for (int i = 1; i < 8; ++i) {
      ma4 = pkmax(ma4, pk_a[i]);
      mb4 = pkmax(mb4, pk_b[i]);
    }
    ma4 = pkmax(ma4, ma4 >> 16);  // lo half = lane max of query a
    mb4 = pkmax(mb4, mb4 >> 16);
    const unsigned lm = (ma4 & 0xffffu) | (mb4 << 16);

    // wave max via packed shuffle reduce (both queries in one chain)
    unsigned mxp = lm;
#pragma unroll
    for (int j = 1; j <= 32; j <<= 1)
      mxp = pkmax(mxp, (unsigned)__shfl_xor((int)mxp, j));
    const float mxa = (float)u2h16((unsigned short)(mxp & 0xffffu));
    const float mxb = (float)u2h16((unsigned short)(mxp >> 16));

    // exact 34th-largest lane-max via ballot bisection on 16-bit keys
    const unsigned keyA = okey16(lm & 0xffffu);
    const unsigned keyB = okey16(lm >> 16);
    unsigned ansA = 0u, ansB = 0u;
#pragma unroll
    for (int bit = 15; bit >= 0; --bit) {
      const unsigned cA = ansA | (1u << bit);
      const unsigned cB = ansB | (1u << bit);
      const int cntA = (int)__popcll(__ballot(keyA >= cA));
      const int cntB = (int)__popcll(__ballot(keyB >= cB));
      if (cntA >= U_TOP) ansA = cA;
      if (cntB >= U_TOP) ansB = cB;
    }
    const _Float16 hTa = u2h16(ikey16(ansA));
    const _Float16 hTb = u2h16(ikey16(ansB));

    // ---- compaction: per-lane keep masks + one packed prefix scan ----
    unsigned maskA = 0u, maskB = 0u;
#pragma unroll
    for (int i = 0; i < 8; ++i) {
      const unsigned pa = pk_a[i], pb = pk_b[i];
      if (u2h16((unsigned short)pa) >= hTa) maskA |= (1u << (2 * i));
      if (u2h16((unsigned short)(pa >> 16)) >= hTa) maskA |= (2u << (2 * i));
      if (u2h16((unsigned short)pb) >= hTb) maskB |= (1u << (2 * i));
      if (u2h16((unsigned short)(pb >> 16)) >= hTb) maskB |= (2u << (2 * i));
    }
    const unsigned cntpk =
        (unsigned)__popc(maskA) | ((unsigned)__popc(maskB) << 16);
    unsigned scan = cntpk;
#pragma unroll
    for (int d = 1; d < 64; d <<= 1) {
      unsigned y = (unsigned)__shfl_up((int)scan, d);
      if (lane >= d) scan += y;
    }
    const unsigned pre = scan - cntpk;
    const unsigned tot = (unsigned)__shfl((int)scan, 63);
    int ca = (int)(tot & 0xffffu), cb = (int)(tot >> 16);
    int pA = (int)(pre & 0xffffu), pB = (int)(pre >> 16);
#pragma unroll
    for (int i = 0; i < 8; ++i) {
      const unsigned pa = pk_a[i], pb = pk_b[i];
      const int jb = 2 * lane + 128 * i;
      if (maskA & (1u << (2 * i))) {
        if (pA < 64) plist[qa][pA] = ((unsigned)jb << 16) | (pa & 0xffffu);
        ++pA;
      }
      if (maskA & (2u << (2 * i))) {
        if (pA < 64) plist[qa][pA] = ((unsigned)(jb + 1) << 16) | (pa >> 16);
        ++pA;
      }
      if (maskB & (1u << (2 * i))) {
        if (pB < 64) plist[qb2][pB] = ((unsigned)jb << 16) | (pb & 0xffffu);
        ++pB;
      }
      if (maskB & (2u << (2 * i))) {
        if (pB < 64) plist[qb2][pB] = ((unsigned)(jb + 1) << 16) | (pb >> 16);
        ++pB;
      }
    }

    // rare fallback: >64 candidates -> bisection to tighter threshold
    if (__builtin_expect(ca > 64, 0)) {
      unsigned ans = 0u;
      int cge = ca;
      bool ex = false;
      for (int bit = 31; bit >= 0 && cge > 64 && !ex; --bit) {
        unsigned cand = ans | (1u << bit);
        float fc = keyinv(cand);
        int c = 0;
#pragma unroll
        for (int i = 0; i < 16; ++i)
          c += (int)__popcll(__ballot((float)sa[lane + 64 * i] >= fc));
        if (c >= U_TOP) { ans = cand; cge = c; ex = (c == U_TOP); }
      }
      float fa2 = keyinv(ans);
      int cc = 0;
#pragma unroll
      for (int i = 0; i < 16; ++i) {
        float va = (float)sa[lane + 64 * i];
        bool ka = va >= fa2;
        unsigned long long ma = __ballot(ka);
        if (ka) {
          int p = cc + mbcnt64(ma);
          if (p < 64)
            plist[qa][p] = ((unsigned)(lane + 64 * i) << 16) | h2u(va);
        }
        cc += (int)__popcll(ma);
      }
      ca = cc;
    }
    if (__builtin_expect(cb > 64, 0)) {
      unsigned ans = 0u;
      int cge = cb;
      bool ex = false;
      for (int bit = 31; bit >= 0 && cge > 64 && !ex; --bit) {
        unsigned cand = ans | (1u << bit);
        float fc = keyinv(cand);
        int c = 0;
#pragma unroll
        for (int i = 0; i < 16; ++i)
          c += (int)__popcll(__ballot((float)sb[lane + 64 * i] >= fc));
        if (c >= U_TOP) { ans = cand; cge = c; ex = (c == U_TOP); }
      }
      float fb2 = keyinv(ans);
      int cc = 0;
#pragma unroll
      for (int i = 0; i < 16; ++i) {
        float vb = (float)sb[lane + 64 * i];
        bool kb = vb >= fb2;
        unsigned long long mb = __ballot(kb);
        if (kb) {
          int p = cc + mbcnt64(mb);
          if (p < 64)
            plist[qb2][p] = ((unsigned)(lane + 64 * i) << 16) | h2u(vb);
        }
        cc += (int)__popcll(mb);
      }
      cb = cc;
    }
    ca = ca > 64 ? 64 : ca;
    cb = cb > 64 ? 64 : cb;

    // one candidate per lane; bisection over candidate keys -> exact 34th
    const unsigned pua = (lane < ca) ? plist[qa][lane] : 0u;
    const unsigned pub = (lane < cb) ? plist[qb2][lane] : 0u;
    const unsigned k2a = (lane < ca) ? okey16(pua & 0xffffu) : 0u;
    const unsigned k2b = (lane < cb) ? okey16(pub & 0xffffu) : 0u;
    unsigned an2A = 0u, an2B = 0u;
#pragma unroll
    for (int bit = 15; bit >= 0; --bit) {
      const unsigned cA = an2A | (1u << bit);
      const unsigned cB = an2B | (1u << bit);
      const int cntA = (int)__popcll(__ballot(k2a >= cA));
      const int cntB = (int)__popcll(__ballot(k2b >= cB));
      if (cntA >= U_TOP) an2A = cA;
      if (cntB >= U_TOP) an2B = cB;
    }
    const _Float16 tha = u2h16(ikey16(an2A));
    const _Float16 thb = u2h16(ikey16(an2B));

    // final keep set; exp only now
    const bool keepa = (lane < ca) && (u2h16((unsigned short)pua) >= tha);
    const bool keepb = (lane < cb) && (u2h16((unsigned short)pub) >= thb);
    unsigned long long kma = __ballot(keepa);
    unsigned long long kmb = __ballot(keepb);
    const int na = (int)__popcll(kma), nb = (int)__popcll(kmb);
    float ea = keepa ? __expf((float)u2h16((unsigned short)pua) - mxa) : 0.f;
    float eb = keepb ? __expf((float)u2h16((unsigned short)pub) - mxb) : 0.f;
    float za = ea, zb = eb;
#pragma unroll
    for (int off = 32; off; off >>= 1) {
      za += __shfl_xor(za, off);
      zb += __shfl_xor(zb, off);
    }
    if (keepa) plist[qa][mbcnt64(kma)] = (pua & 0xffff0000u) | h2u(ea);
    if (keepb) plist[qb2][mbcnt64(kmb)] = (pub & 0xffff0000u) | h2u(eb);

    // ---- sparse PV: 4 entry-slots x 16 dim-groups, dwordx2 loads ----
    const ushort_t* vbase = Vb + (size_t)b * SEQ * DMODEL + h * DK;
    const int slot = lane >> 4;   // 0..3: which entry within a 4-block
    const int dgrp = lane & 15;   // dims [4*dgrp, 4*dgrp+4)
    const int d4 = dgrp * 4;
    float aA0 = 0.f, aA1 = 0.f, aA2 = 0.f, aA3 = 0.f;
    float aB0 = 0.f, aB1 = 0.f, aB2 = 0.f, aB3 = 0.f;
    const int nmax = na > nb ? na : nb;
    for (int i = slot; i < nmax; i += 4) {
      const unsigned ua = (i < na) ? plist[qa][i] : 0u;   // weight 0 if OOB
      const unsigned ub = (i < nb) ? plist[qb2][i] : 0u;
      const uint2 va =
          *(const uint2*)(vbase + (size_t)(ua >> 16) * DMODEL + d4);
      const uint2 vb =
          *(const uint2*)(vbase + (size_t)(ub >> 16) * DMODEL + d4);
      const float wa = (float)u2h16((unsigned short)ua);
      const float wb = (float)u2h16((unsigned short)ub);
      aA0 += wa * __uint_as_float(va.x << 16);
      aA1 += wa * __uint_as_float(va.x & 0xffff0000u);
      aA2 += wa * __uint_as_float(va.y << 16);
      aA3 += wa * __uint_as_float(va.y & 0xffff0000u);
      aB0 += wb * __uint_as_float(vb.x << 16);
      aB1 += wb * __uint_as_float(vb.x & 0xffff0000u);
      aB2 += wb * __uint_as_float(vb.y << 16);
      aB3 += wb * __uint_as_float(vb.y & 0xffff0000u);
    }
    // reduce over the 4 entry-slots (lanes g, g+16, g+32, g+48)
    aA0 += __shfl_xor(aA0, 16); aA0 += __shfl_xor(aA0, 32);
    aA1 += __shfl_xor(aA1, 16); aA1 += __shfl_xor(aA1, 32);
    aA2 += __shfl_xor(aA2, 16); aA2 += __shfl_xor(aA2, 32);
    aA3 += __shfl_xor(aA3, 16); aA3 += __shfl_xor(aA3, 32);
    aB0 += __shfl_xor(aB0, 16); aB0 += __shfl_xor(aB0, 32);
    aB1 += __shfl_xor(aB1, 16); aB1 += __shfl_xor(aB1, 32);
    aB2 += __shfl_xor(aB2, 16); aB2 += __shfl_xor(aB2, 32);
    aB3 += __shfl_xor(aB3, 16); aB3 += __shfl_xor(aB3, 32);

    const float iza = 1.f / za, izb = 1.f / zb;
    if (slot == 0) {
      uint2 o;
      o.x = (unsigned)f2bf(aA0 * iza) | ((unsigned)f2bf(aA1 * iza) << 16);
      o.y = (unsigned)f2bf(aA2 * iza) | ((unsigned)f2bf(aA3 * iza) << 16);
      *(uint2*)(Ob + (size_t)(b * SEQ + q0 + qa) * DMODEL + h * DK + d4) = o;
    } else if (slot == 1) {
      uint2 o;
      o.x = (unsigned)f2bf(aB0 * izb) | ((unsigned)f2bf(aB1 * izb) << 16);
      o.y = (unsigned)f2bf(aB2 * izb) | ((unsigned)f2bf(aB3 * izb) << 16);
      *(uint2*)(Ob + (size_t)(b * SEQ + q0 + qb2) * DMODEL + h * DK + d4) = o;
    }
  }
}

// ---------------------------------------------------------------------------
// Orchestration (R9 verified-best config).  ws layout (MiB): ffh/qkv [0,16)
// (Wo partials reuse [0,8) after attn) | ao [16,20) (xb pre-loop; FFN2
// partials reuse [16,24)) | [20,24) FFN2 partial 1 | hb [24,28) |
// wt [28, 46.2).
// Layer GEMMs: BK=64 2-phase dbuf. FFN1 BN=128 (512 blk); QKV BN=64
// (768 blk); Wo/FFN2 split-K BN=64 (512 blk each).
// ---------------------------------------------------------------------------
extern "C" void kernel_launch(void* const* d_in, const int* in_sizes, int n_in,
                              void* d_out, int out_size, void* d_ws,
                              size_t ws_size, hipStream_t stream) {
  const float* x = (const float*)d_in[0];
  const float* W_emb = (const float*)d_in[1];
  const float* b_emb = (const float*)d_in[2];
  const float* Wq = (const float*)d_in[3];
  const float* bq = (const float*)d_in[4];
  const float* Wk = (const float*)d_in[5];
  const float* bk = (const float*)d_in[6];
  const float* Wv = (const float*)d_in[7];
  const float* bv = (const float*)d_in[8];
  const float* Wo = (const float*)d_in[9];
  const float* bo = (const float*)d_in[10];
  const float* ln1_g = (const float*)d_in[11];
  const float* ln1_b = (const float*)d_in[12];
  const float* W1 = (const float*)d_in[13];
  const float* b1 = (const float*)d_in[14];
  const float* W2 = (const float*)d_in[15];
  const float* b2 = (const float*)d_in[16];
  const float* ln2_g = (const float*)d_in[17];
  const float* ln2_b = (const float*)d_in[18];
  const float* W_dec = (const float*)d_in[19];
  const float* b_dec = (const float*)d_in[20];

  char* wsb = (char*)d_ws;
  ushort_t* qkv = (ushort_t*)wsb;
  ushort_t* ffh = (ushort_t*)wsb;
  ushort_t* wop = (ushort_t*)wsb;  // Wo partials [0,8M)
  ushort_t* ao = (ushort_t*)(wsb + ((size_t)16 << 20));
  ushort_t* xb = (ushort_t*)(wsb + ((size_t)16 << 20));
  ushort_t* ffp = (ushort_t*)(wsb + ((size_t)16 << 20));  // FFN2 partials
  ushort_t* hb = (ushort_t*)(wsb + ((size_t)24 << 20));
  short* wt = (short*)(wsb + ((size_t)28 << 20));
  short* wembT = wt + 9437184;
  short* wdecT = wt + 9502720;

  f32_to_bf16_kernel<<<dim3(512), 256, 0, stream>>>(x, xb);
  convert_all<<<dim3(9312), dim3(32, 8), 0, stream>>>(Wq, Wk, Wv, Wo, W1, W2,
                                                      W_emb, W_dec, wt);
  // embed: hb = bf16((xb @ W_emb + b_emb)*sqrt(512) + PE)
  gemm64<0, 1, 2, 0><<<dim3(8, 64), 256, 0, stream>>>(
      xb, wembT, b_emb, (void*)hb, nullptr, 128, 512);

  for (int i = 0; i < 3; ++i) {
    short* wtL = wt + (size_t)i * 3145728;

    // QKV: one N=1536 GEMM on 128x64 tiles (768 blocks, 3/CU)
    gemmT<0, 1, 64><<<dim3(24, 32), 256, 0, stream>>>(
        hb, wtL, bq + i * DMODEL, bk + i * DMODEL, bv + i * DMODEL, qkv, 512,
        512, 2097152);

    attn_kernel<<<dim3(SEQ / 16, NHEAD, BATCH), dim3(512), 0, stream>>>(
        qkv, qkv + 2097152, qkv + 4194304, ao);

    // Wo split-K (K=512 -> 2x256), 128x64 tiles (512 blocks, 2/CU)
    gemmskT<64><<<dim3(8, 32, 2), 256, 0, stream>>>(
        ao, wtL + 786432, bo + i * DMODEL, wop, 512, 256);
    ln_red_kernel<<<dim3(ROWS / 4), 256, 0, stream>>>(
        wop, wop + 2097152, ln1_g + i * DMODEL, ln1_b + i * DMODEL, hb);

    // FFN1 N=2048 on 128x128 tiles (512 blocks, 2/CU, 250B staged/MFMA)
    gemmT<1, 0, 128><<<dim3(16, 32), 256, 0, stream>>>(
        hb, wtL + 1048576, b1 + i * DFF, nullptr, nullptr, ffh, 512, 2048, 0);
    // FFN2 split-K (K=2048 -> 2x1024), 128x64 tiles (512 blocks, 2/CU)
    gemmskT<64><<<dim3(8, 32, 2), 256, 0, stream>>>(
        ffh, wtL + 2097152, b2 + i * DMODEL, ffp, 2048, 1024);
    ln_red_kernel<<<dim3(ROWS / 4), 256, 0, stream>>>(
        ffp, ffp + 2097152, ln2_g + i * DMODEL, ln2_b + i * DMODEL, hb);
  }

  gemm64<0, 0, 0, 0><<<dim3(1, 64), 256, 0, stream>>>(
      hb, wdecT, b_dec, d_out, nullptr, 512, 64);
}

// Round 14
// 486.643 us; speedup vs baseline: 1.0301x; 1.0028x over previous
//
#include <hip/hip_runtime.h>
#include <math.h>

#define SEQ 1024
#define BATCH 4
#define DMODEL 512
#define NHEAD 8
#define DK 64
#define DFF 2048
#define U_TOP 34
#define ROWS (BATCH * SEQ)

typedef unsigned short ushort_t;
typedef __attribute__((ext_vector_type(8))) short short8;
typedef __attribute__((ext_vector_type(4))) float float4v;
typedef __attribute__((ext_vector_type(2))) _Float16 h2v;

__device__ inline ushort_t f2bf(float f) {
  unsigned u = __float_as_uint(f);
  unsigned r = u + 0x7fffu + ((u >> 16) & 1u);
  return (ushort_t)(r >> 16);
}
__device__ inline float bf2f(ushort_t u) {
  return __uint_as_float((unsigned)u << 16);
}
// ordered-uint key -> float (rare >64-candidate fallback only)
__device__ inline float keyinv(unsigned cand) {
  unsigned fb = (cand & 0x80000000u) ? (cand ^ 0x80000000u) : ~cand;
  return __uint_as_float(fb);
}

union H16 { _Float16 h; unsigned short u; };
__device__ inline unsigned short h2u(float f) {
  H16 t; t.h = (_Float16)f; return t.u;
}
__device__ inline float u2h(unsigned short u) {
  H16 t; t.u = u; return (float)t.h;
}
__device__ inline _Float16 u2h16(unsigned short u) {
  H16 t; t.u = u; return t.h;
}
// fp16 bits -> 16-bit ordered key (unsigned compare == float compare)
__device__ inline unsigned okey16(unsigned b) {
  return (b ^ (0x8000u | ((b >> 15) * 0x7FFFu))) & 0xFFFFu;
}
// inverse of okey16
__device__ inline unsigned short ikey16(unsigned k) {
  return (unsigned short)(k ^ ((k >> 15) ? 0x8000u : 0xFFFFu));
}
__device__ inline int mbcnt64(unsigned long long m) {
  int lo = __builtin_amdgcn_mbcnt_lo((unsigned)m, 0);
  return __builtin_amdgcn_mbcnt_hi((unsigned)(m >> 32), lo);
}

__device__ inline void glds16(const void* g, void* l) {
  __builtin_amdgcn_global_load_lds(
      (const __attribute__((address_space(1))) unsigned int*)g,
      (__attribute__((address_space(3))) unsigned int*)l, 16, 0, 0);
}

// packed fp16 max (v_pk_max_f16)
__device__ inline unsigned pkmax(unsigned a, unsigned b) {
  return __builtin_bit_cast(unsigned, __builtin_elementwise_max(
      __builtin_bit_cast(h2v, a), __builtin_bit_cast(h2v, b)));
}

// ---------------------------------------------------------------------------
// bf16 MFMA GEMM, 128xBN tile (BN in {64,128}), BK=64 staged as TWO adjacent
// BK=32 sub-tiles, 2-phase double-buffered K-loop: stage(t+1) issued BEFORE
// the ds_read+MFMA of tile t; ONE barrier per 64-wide K-step.
// BN=64: 48KB LDS -> 3 blocks/CU (QKV). BN=128: 64KB -> 2 blocks/CU but
// 250B staged/MFMA (FFN1, N=2048).
// XCD swizzle: each XCD owns a band of row-tiles (A fetched once per band).
// SPLIT=1 (QKV): Bt has 1536 rows (Wq|Wk|Wv); z=bn>>9 routes output/bias.
// Requires gridDim.y % 8 == 0 and K % 64 == 0.
// ---------------------------------------------------------------------------
template <int RELU, int SPLIT, int BN>
__global__ __launch_bounds__(256) void gemmT(
    const ushort_t* __restrict__ A, const short* __restrict__ Bt,
    const float* __restrict__ b0, const float* __restrict__ b1,
    const float* __restrict__ b2, ushort_t* __restrict__ Cout,
    int K, int N, int zCstride) {
  constexpr int NT = BN / 32;  // n-tiles per wave (wave covers BN/2 cols)
  __shared__ short As[2][2][128 * 32];
  __shared__ short Bs[2][2][BN * 32];

  const int tid = threadIdx.x;
  const int lane = tid & 63, w = tid >> 6;
  const int wm = w >> 1, wn = w & 1;
  const int quad = lane >> 4, r16 = lane & 15;

  // XCD-affinity block swizzle (round-robin id%8 -> XCD heuristic)
  const int id = blockIdx.y * gridDim.x + blockIdx.x;
  const int xcd = id & 7;
  const int loc = id >> 3;
  const int rpx = gridDim.y >> 3;  // row-tiles per XCD
  const int bm = (xcd * rpx + (loc % rpx)) * 128;
  const int bn = (loc / rpx) * BN;

  const int srow = lane >> 2, skseg = lane & 3;
  const ushort_t* Ag0 = A + (size_t)(bm + w * 16 + srow) * K + skseg * 8;
  const ushort_t* Ag1 = Ag0 + (size_t)64 * K;
  const short* Bg0 = Bt + (size_t)(bn + w * 16 + srow) * K + skseg * 8;
  const short* Bg1 = Bg0 + (size_t)64 * K;
  const int aoff0 = (w * 16) * 32;
  const int aoff1 = (64 + w * 16) * 32;
  const int boff0 = (w * 16) * 32;
  const int boff1 = (64 + w * 16) * 32;

  float4v acc[4][NT];
#pragma unroll
  for (int m = 0; m < 4; ++m)
#pragma unroll
    for (int n = 0; n < NT; ++n) acc[m][n] = (float4v){0.f, 0.f, 0.f, 0.f};

  // stage one 64-wide K-tile (two 32-wide halves) into buffer bi
  auto stage = [&](int k0, int bi) {
#pragma unroll
    for (int hh = 0; hh < 2; ++hh) {
      glds16(Ag0 + k0 + hh * 32, &As[bi][hh][aoff0]);
      glds16(Ag1 + k0 + hh * 32, &As[bi][hh][aoff1]);
      glds16(Bg0 + k0 + hh * 32, &Bs[bi][hh][boff0]);
      if (BN == 128) glds16(Bg1 + k0 + hh * 32, &Bs[bi][hh][boff1]);
    }
  };

  stage(0, 0);
  __syncthreads();  // compiler emits vmcnt(0) before barrier

  int cur = 0;
  for (int k0 = 0; k0 < K; k0 += 64) {
    if (k0 + 64 < K) stage(k0 + 64, cur ^ 1);

#pragma unroll
    for (int hh = 0; hh < 2; ++hh) {
      short8 af[4], bfr[NT];
#pragma unroll
      for (int m = 0; m < 4; ++m)
        af[m] = *(const short8*)&As[cur][hh][(wm * 64 + m * 16 + r16) * 32 +
                                             quad * 8];
#pragma unroll
      for (int n = 0; n < NT; ++n)
        bfr[n] = *(const short8*)&Bs[cur][hh][(wn * (BN / 2) + n * 16 + r16) *
                                                  32 +
                                              quad * 8];
#pragma unroll
      for (int m = 0; m < 4; ++m)
#pragma unroll
        for (int n = 0; n < NT; ++n)
          acc[m][n] = __builtin_amdgcn_mfma_f32_16x16x32_bf16(
              af[m], bfr[n], acc[m][n], 0, 0, 0);
    }
    __syncthreads();  // drains new stage + ds_reads; 1 barrier per 64-K step
    cur ^= 1;
  }

  const int z = SPLIT ? (bn >> 9) : 0;
  const float* bias = (z == 0) ? b0 : (z == 1 ? b1 : b2);
  const int cbase = SPLIT ? (bn & 511) : bn;
  const int strideN = SPLIT ? 512 : N;
  ushort_t* C = Cout + (SPLIT ? (size_t)z * zCstride : (size_t)0);

  float bias_n[NT];
#pragma unroll
  for (int n = 0; n < NT; ++n)
    bias_n[n] = bias[cbase + wn * (BN / 2) + n * 16 + r16];

#pragma unroll
  for (int m = 0; m < 4; ++m) {
#pragma unroll
    for (int n = 0; n < NT; ++n) {
      int col = cbase + wn * (BN / 2) + n * 16 + r16;
#pragma unroll
      for (int reg = 0; reg < 4; ++reg) {
        int row = bm + wm * 64 + m * 16 + quad * 4 + reg;
        float v = acc[m][n][reg] + bias_n[n];
        if (RELU) v = fmaxf(v, 0.f);
        C[(size_t)row * strideN + col] = f2bf(v);
      }
    }
  }
}

// ---------------------------------------------------------------------------
// Split-K bf16 MFMA GEMM, 128xBN tile over K-range [z*Ks, (z+1)*Ks).
// Same BK=64 two-half 2-phase K-loop as gemmT. Requires Ks % 64 == 0.
// Writes bf16 partials to pout + z*2097152 (N fixed 512). Bias on z==0.
// ---------------------------------------------------------------------------
template <int BN>
__global__ __launch_bounds__(256) void gemmskT(
    const ushort_t* __restrict__ A, const short* __restrict__ Bt,
    const float* __restrict__ bias, ushort_t* __restrict__ pout,
    int K, int Ks) {
  constexpr int NT = BN / 32;
  __shared__ short As[2][2][128 * 32];
  __shared__ short Bs[2][2][BN * 32];

  const int tid = threadIdx.x;
  const int lane = tid & 63, w = tid >> 6;
  const int wm = w >> 1, wn = w & 1;
  const int quad = lane >> 4, r16 = lane & 15;

  const int id = blockIdx.y * gridDim.x + blockIdx.x;
  const int xcd = id & 7;
  const int loc = id >> 3;
  const int rpx = gridDim.y >> 3;
  const int bm = (xcd * rpx + (loc % rpx)) * 128;
  const int bn = (loc / rpx) * BN;
  const int z = blockIdx.z;
  const int koff = z * Ks;

  const int srow = lane >> 2, skseg = lane & 3;
  const ushort_t* Ag0 =
      A + (size_t)(bm + w * 16 + srow) * K + skseg * 8 + koff;
  const ushort_t* Ag1 = Ag0 + (size_t)64 * K;
  const short* Bg0 = Bt + (size_t)(bn + w * 16 + srow) * K + skseg * 8 + koff;
  const short* Bg1 = Bg0 + (size_t)64 * K;
  const int aoff0 = (w * 16) * 32;
  const int aoff1 = (64 + w * 16) * 32;
  const int boff0 = (w * 16) * 32;
  const int boff1 = (64 + w * 16) * 32;

  float4v acc[4][NT];
#pragma unroll
  for (int m = 0; m < 4; ++m)
#pragma unroll
    for (int n = 0; n < NT; ++n) acc[m][n] = (float4v){0.f, 0.f, 0.f, 0.f};

  auto stage = [&](int k0, int bi) {
#pragma unroll
    for (int hh = 0; hh < 2; ++hh) {
      glds16(Ag0 + k0 + hh * 32, &As[bi][hh][aoff0]);
      glds16(Ag1 + k0 + hh * 32, &As[bi][hh][aoff1]);
      glds16(Bg0 + k0 + hh * 32, &Bs[bi][hh][boff0]);
      if (BN == 128) glds16(Bg1 + k0 + hh * 32, &Bs[bi][hh][boff1]);
    }
  };

  stage(0, 0);
  __syncthreads();

  int cur = 0;
  for (int k0 = 0; k0 < Ks; k0 += 64) {
    if (k0 + 64 < Ks) stage(k0 + 64, cur ^ 1);

#pragma unroll
    for (int hh = 0; hh < 2; ++hh) {
      short8 af[4], bfr[NT];
#pragma unroll
      for (int m = 0; m < 4; ++m)
        af[m] = *(const short8*)&As[cur][hh][(wm * 64 + m * 16 + r16) * 32 +
                                             quad * 8];
#pragma unroll
      for (int n = 0; n < NT; ++n)
        bfr[n] = *(const short8*)&Bs[cur][hh][(wn * (BN / 2) + n * 16 + r16) *
                                                  32 +
                                              quad * 8];
#pragma unroll
      for (int m = 0; m < 4; ++m)
#pragma unroll
        for (int n = 0; n < NT; ++n)
          acc[m][n] = __builtin_amdgcn_mfma_f32_16x16x32_bf16(
              af[m], bfr[n], acc[m][n], 0, 0, 0);
    }
    __syncthreads();
    cur ^= 1;
  }

  ushort_t* P = pout + (size_t)z * 2097152;
  float bias_n[NT];
#pragma unroll
  for (int n = 0; n < NT; ++n)
    bias_n[n] = (z == 0) ? bias[bn + wn * (BN / 2) + n * 16 + r16] : 0.f;

#pragma unroll
  for (int m = 0; m < 4; ++m) {
#pragma unroll
    for (int n = 0; n < NT; ++n) {
      int col = bn + wn * (BN / 2) + n * 16 + r16;
#pragma unroll
      for (int reg = 0; reg < 4; ++reg) {
        int row = bm + wm * 64 + m * 16 + quad * 4 + reg;
        float v = acc[m][n][reg] + bias_n[n];
        P[(size_t)row * 512 + col] = f2bf(v);
      }
    }
  }
}

// ---------------------------------------------------------------------------
// bf16 MFMA GEMM, tile 64x64 (embed + decode only), BK=64 two-half 2-phase.
// EPI 0: none. EPI 2: v = v*sqrt(512) + positional encoding (embed).
// Requires K % 64 == 0 (embed K=128, decode K=512).
// ---------------------------------------------------------------------------
template <int RELU, int OUTBF16, int EPI, int ADDC>
__global__ __launch_bounds__(256) void gemm64(
    const ushort_t* __restrict__ A, const short* __restrict__ Bt,
    const float* __restrict__ bias, void* __restrict__ Cout,
    const ushort_t* __restrict__ Cadd, int K, int N) {
  __shared__ short As[2][2][64 * 32];
  __shared__ short Bs[2][2][64 * 32];

  const int tid = threadIdx.x;
  const int lane = tid & 63, w = tid >> 6;
  const int wm = w >> 1, wn = w & 1;
  const int quad = lane >> 4, r16 = lane & 15;
  const int bm = blockIdx.y * 64, bn = blockIdx.x * 64;

  const int srow = tid >> 2, skseg = tid & 3;
  const ushort_t* Ag = A + (size_t)(bm + srow) * K + skseg * 8;
  const short* Bg = Bt + (size_t)(bn + srow) * K + skseg * 8;
  const int loff = w * 512;

  float4v acc[2][2];
#pragma unroll
  for (int m = 0; m < 2; ++m)
#pragma unroll
    for (int n = 0; n < 2; ++n) acc[m][n] = (float4v){0.f, 0.f, 0.f, 0.f};

  auto stage = [&](int k0, int bi) {
#pragma unroll
    for (int hh = 0; hh < 2; ++hh) {
      glds16(Ag + k0 + hh * 32, &As[bi][hh][loff]);
      glds16(Bg + k0 + hh * 32, &Bs[bi][hh][loff]);
    }
  };

  stage(0, 0);
  __syncthreads();

  int cur = 0;
  for (int k0 = 0; k0 < K; k0 += 64) {
    if (k0 + 64 < K) stage(k0 + 64, cur ^ 1);

#pragma unroll
    for (int hh = 0; hh < 2; ++hh) {
      short8 af[2], bfr[2];
#pragma unroll
      for (int m = 0; m < 2; ++m)
        af[m] = *(const short8*)&As[cur][hh][(wm * 32 + m * 16 + r16) * 32 +
                                             quad * 8];
#pragma unroll
      for (int n = 0; n < 2; ++n)
        bfr[n] = *(const short8*)&Bs[cur][hh][(wn * 32 + n * 16 + r16) * 32 +
                                              quad * 8];
#pragma unroll
      for (int m = 0; m < 2; ++m)
#pragma unroll
        for (int n = 0; n < 2; ++n)
          acc[m][n] = __builtin_amdgcn_mfma_f32_16x16x32_bf16(
              af[m], bfr[n], acc[m][n], 0, 0, 0);
    }
    __syncthreads();
    cur ^= 1;
  }

  const float pe_c = (float)(-9.210340371976184 / 512.0);
  const float sqrtd = 22.62741699796952f;

  float bias_n[2];
#pragma unroll
  for (int n = 0; n < 2; ++n) bias_n[n] = bias[bn + wn * 32 + n * 16 + r16];

#pragma unroll
  for (int m = 0; m < 2; ++m) {
#pragma unroll
    for (int n = 0; n < 2; ++n) {
      int col = bn + wn * 32 + n * 16 + r16;
#pragma unroll
      for (int reg = 0; reg < 4; ++reg) {
        int row = bm + wm * 32 + m * 16 + quad * 4 + reg;
        float v = acc[m][n][reg] + bias_n[n];
        if (RELU) v = fmaxf(v, 0.f);
        if (EPI == 2) {
          int pos = row & (SEQ - 1);
          float e = __expf((float)(col & ~1) * pe_c);
          float arg = (float)pos * e;
          v = v * sqrtd + ((col & 1) ? __cosf(arg) : __sinf(arg));
        }
        if (ADDC) v += bf2f(Cadd[(size_t)row * N + col]);
        if (OUTBF16) {
          ((ushort_t*)Cout)[(size_t)row * N + col] = f2bf(v);
        } else {
          ((float*)Cout)[(size_t)row * N + col] = v;
        }
      }
    }
  }
}

// ---------------------------------------------------------------------------
// All weights (3 layers + emb + dec): W[K][N] f32 -> Wt[N][K] bf16, 1 launch.
// ---------------------------------------------------------------------------
__global__ __launch_bounds__(256) void convert_all(
    const float* __restrict__ Wq, const float* __restrict__ Wk,
    const float* __restrict__ Wv, const float* __restrict__ Wo,
    const float* __restrict__ W1, const float* __restrict__ W2,
    const float* __restrict__ W_emb, const float* __restrict__ W_dec,
    short* __restrict__ wt) {
  __shared__ float t[32][33];
  int id = blockIdx.x;
  const float* src;
  short* dst;
  int K, N, tk, tn;
  if (id < 9216) {
    int lay = id / 3072, r = id % 3072;
    short* wl = wt + (size_t)lay * 3145728;
    const size_t wsz = 512 * 512;
    if (r < 1024) {
      int wi = r >> 8, tile = r & 255;
      const float* base = (wi == 0) ? Wq : (wi == 1) ? Wk : (wi == 2) ? Wv : Wo;
      src = base + lay * wsz;
      dst = wl + wi * 262144;
      K = 512; N = 512; tk = tile >> 4; tn = tile & 15;
    } else if (r < 2048) {
      int tile = r - 1024;
      src = W1 + (size_t)lay * 512 * 2048;
      dst = wl + 1048576;
      K = 512; N = 2048; tk = tile >> 6; tn = tile & 63;
    } else {
      int tile = r - 2048;
      src = W2 + (size_t)lay * 2048 * 512;
      dst = wl + 2097152;
      K = 2048; N = 512; tk = tile >> 4; tn = tile & 15;
    }
  } else {
    int r = id - 9216;
    if (r < 64) {
      src = W_emb; dst = wt + 9437184; K = 128; N = 512; tk = r >> 4; tn = r & 15;
    } else {
      r -= 64;
      src = W_dec; dst = wt + 9502720; K = 512; N = 64; tk = r >> 1; tn = r & 1;
    }
  }
  const int k0 = tk * 32, n0 = tn * 32;
  const int tx = threadIdx.x, ty = threadIdx.y;
#pragma unroll
  for (int i = 0; i < 4; ++i) {
    int r = ty + i * 8;
    t[r][tx] = src[(size_t)(k0 + r) * N + n0 + tx];
  }
  __syncthreads();
#pragma unroll
  for (int i = 0; i < 4; ++i) {
    int r = ty + i * 8;
    dst[(size_t)(n0 + r) * K + k0 + tx] = (short)f2bf(t[tx][r]);
  }
}

__global__ __launch_bounds__(256) void f32_to_bf16_kernel(
    const float* __restrict__ src, ushort_t* __restrict__ dst) {
  int i = blockIdx.x * blockDim.x + threadIdx.x;
  float4 v = ((const float4*)src)[i];
  ushort4 o;
  o.x = f2bf(v.x); o.y = f2bf(v.y); o.z = f2bf(v.z); o.w = f2bf(v.w);
  ((ushort4*)dst)[i] = o;
}

// ---------------------------------------------------------------------------
// Split-K reduce + residual + LayerNorm: hb = LN(pa + pb + hb) * g + b.
// ---------------------------------------------------------------------------
__global__ __launch_bounds__(256) void ln_red_kernel(
    const ushort_t* __restrict__ pa, const ushort_t* __restrict__ pb,
    const float* __restrict__ g, const float* __restrict__ bb,
    ushort_t* __restrict__ hb) {
  const int row = blockIdx.x * 4 + (threadIdx.x >> 6);
  const int lane = threadIdx.x & 63;
  const size_t base = (size_t)row * DMODEL + lane * 8;
  uint4 ra = *(const uint4*)(pa + base);
  uint4 rb = *(const uint4*)(pb + base);
  uint4 rh = *(const uint4*)(hb + base);
  unsigned aa[4] = {ra.x, ra.y, ra.z, ra.w};
  unsigned ab[4] = {rb.x, rb.y, rb.z, rb.w};
  unsigned ah[4] = {rh.x, rh.y, rh.z, rh.w};
  float v[8];
#pragma unroll
  for (int k = 0; k < 4; ++k) {
    v[2 * k] = bf2f((ushort_t)(aa[k] & 0xffff)) +
               bf2f((ushort_t)(ab[k] & 0xffff)) +
               bf2f((ushort_t)(ah[k] & 0xffff));
    v[2 * k + 1] = bf2f((ushort_t)(aa[k] >> 16)) +
                   bf2f((ushort_t)(ab[k] >> 16)) +
                   bf2f((ushort_t)(ah[k] >> 16));
  }
  float sum = 0.f, sq = 0.f;
#pragma unroll
  for (int k = 0; k < 8; ++k) { sum += v[k]; sq += v[k] * v[k]; }
#pragma unroll
  for (int off = 32; off; off >>= 1) {
    sum += __shfl_xor(sum, off);
    sq += __shfl_xor(sq, off);
  }
  float mean = sum * (1.f / 512.f);
  float var = fmaxf(sq * (1.f / 512.f) - mean * mean, 0.f);
  float rstd = 1.f / sqrtf(var + 1e-5f);
  float4 g0 = *(const float4*)(g + lane * 8);
  float4 g1 = *(const float4*)(g + lane * 8 + 4);
  float4 c0 = *(const float4*)(bb + lane * 8);
  float4 c1 = *(const float4*)(bb + lane * 8 + 4);
  float gg[8] = {g0.x, g0.y, g0.z, g0.w, g1.x, g1.y, g1.z, g1.w};
  float cc[8] = {c0.x, c0.y, c0.z, c0.w, c1.x, c1.y, c1.z, c1.w};
  uint4 out;
  unsigned* op = (unsigned*)&out;
#pragma unroll
  for (int k = 0; k < 4; ++k) {
    float y0 = (v[2 * k] - mean) * rstd * gg[2 * k] + cc[2 * k];
    float y1 = (v[2 * k + 1] - mean) * rstd * gg[2 * k + 1] + cc[2 * k + 1];
    op[k] = (unsigned)f2bf(y0) | ((unsigned)f2bf(y1) << 16);
  }
  *(uint4*)(hb + base) = out;
}

// ---------------------------------------------------------------------------
// ProbSparse attention v13 (verified best: prefix-scan compaction, coalesced
// 4-slot PV; setprio reverted -- R12 showed it costs ~5us at this occupancy).
// ---------------------------------------------------------------------------
#define SST 1048

__global__ __launch_bounds__(512, 8) void attn_kernel(
    const ushort_t* __restrict__ Qb, const ushort_t* __restrict__ Kb,
    const ushort_t* __restrict__ Vb, ushort_t* __restrict__ Ob) {
  __shared__ _Float16 s16[16 * SST];
  __shared__ unsigned plist[16][64];

  const int tid = threadIdx.x;
  // XCD swizzle: grid (64, 8, 4) -> each XCD owns 4 (b,h) pairs x 64 q-tiles
  const int id = blockIdx.x + 64 * (blockIdx.y + 8 * blockIdx.z);
  const int xcd = id & 7;
  const int loc = id >> 3;
  const int bh = xcd * 4 + (loc & 3);
  const int q0 = (loc >> 2) * 16;
  const int b = bh >> 3;
  const int h = bh & 7;

  const int w = tid >> 6;
  const int lane = tid & 63;
  const int quad = lane >> 4, r16 = lane & 15;

  // ---- Phase 1: MFMA scores (16 queries x 128 keys per wave) ----
  {
    const int j0 = w * 128;
    const ushort_t* qrow =
        Qb + (size_t)(b * SEQ + q0 + r16) * DMODEL + h * DK + quad * 8;
    short8 aq0 = *(const short8*)qrow;
    short8 aq1 = *(const short8*)(qrow + 32);

#pragma unroll
    for (int nt = 0; nt < 8; ++nt) {
      const ushort_t* krow =
          Kb + (size_t)(b * SEQ + j0 + nt * 16 + r16) * DMODEL + h * DK +
          quad * 8;
      short8 bk0 = *(const short8*)krow;
      short8 bk1 = *(const short8*)(krow + 32);
      float4v a = (float4v){0.f, 0.f, 0.f, 0.f};
      a = __builtin_amdgcn_mfma_f32_16x16x32_bf16(aq0, bk0, a, 0, 0, 0);
      a = __builtin_amdgcn_mfma_f32_16x16x32_bf16(aq1, bk1, a, 0, 0, 0);
#pragma unroll
      for (int reg = 0; reg < 4; ++reg)
        s16[(quad * 4 + reg) * SST + j0 + nt * 16 + r16] =
            (_Float16)(a[reg] * 0.125f);
    }
  }
  __syncthreads();

  // ---- Phase 2: two queries per wave, scores register-cached ----
  {
    const int qa = w, qb2 = w + 8;
    const _Float16* sa = &s16[qa * SST];
    const _Float16* sb = &s16[qb2 * SST];
    const unsigned* sa32 = (const unsigned*)sa;
    const unsigned* sb32 = (const unsigned*)sb;

    // load all scores once: 8 packed u32 per query
    unsigned pk_a[8], pk_b[8];
#pragma unroll
    for (int i = 0; i < 8; ++i) {
      pk_a[i] = sa32[lane + 64 * i];
      pk_b[i] = sb32[lane + 64 * i];
    }

    // packed lane maxima (fp16)
    unsigned ma4 = pk_a[0], mb4 = pk_b[0];
#pragma unroll
    for (int i = 1; i < 8; ++i) {
      ma4 = pkmax(ma4, pk_a[i]);
      mb4 = pkmax(mb4, pk_b[i]);
    }
    ma4 = pkmax(ma4, ma4 >> 16);  // lo half = lane max of query a
    mb4 = pkmax(mb4, mb4 >> 16);
    const unsigned lm = (ma4 & 0xffffu) | (mb4 << 16);

    // wave max via packed shuffle reduce (both queries in one chain)
    unsigned mxp = lm;
#pragma unroll
    for (int j = 1; j <= 32; j <<= 1)
      mxp = pkmax(mxp, (unsigned)__shfl_xor((int)mxp, j));
    const float mxa = (float)u2h16((unsigned short)(mxp & 0xffffu));
    const float mxb = (float)u2h16((unsigned short)(mxp >> 16));

    // exact 34th-largest lane-max via ballot bisection on 16-bit keys
    const unsigned keyA = okey16(lm & 0xffffu);
    const unsigned keyB = okey16(lm >> 16);
    unsigned ansA = 0u, ansB = 0u;
#pragma unroll
    for (int bit = 15; bit >= 0; --bit) {
      const unsigned cA = ansA | (1u << bit);
      const unsigned cB = ansB | (1u << bit);
      const int cntA = (int)__popcll(__ballot(keyA >= cA));
      const int cntB = (int)__popcll(__ballot(keyB >= cB));
      if (cntA >= U_TOP) ansA = cA;
      if (cntB >= U_TOP) ansB = cB;
    }
    const _Float16 hTa = u2h16(ikey16(ansA));
    const _Float16 hTb = u2h16(ikey16(ansB));

    // ---- compaction: per-lane keep masks + one packed prefix scan ----
    unsigned maskA = 0u, maskB = 0u;
#pragma unroll
    for (int i = 0; i < 8; ++i) {
      const unsigned pa = pk_a[i], pb = pk_b[i];
      if (u2h16((unsigned short)pa) >= hTa) maskA |= (1u << (2 * i));
      if (u2h16((unsigned short)(pa >> 16)) >= hTa) maskA |= (2u << (2 * i));
      if (u2h16((unsigned short)pb) >= hTb) maskB |= (1u << (2 * i));
      if (u2h16((unsigned short)(pb >> 16)) >= hTb) maskB |= (2u << (2 * i));
    }
    const unsigned cntpk =
        (unsigned)__popc(maskA) | ((unsigned)__popc(maskB) << 16);
    unsigned scan = cntpk;
#pragma unroll
    for (int d = 1; d < 64; d <<= 1) {
      unsigned y = (unsigned)__shfl_up((int)scan, d);
      if (lane >= d) scan += y;
    }
    const unsigned pre = scan - cntpk;
    const unsigned tot = (unsigned)__shfl((int)scan, 63);
    int ca = (int)(tot & 0xffffu), cb = (int)(tot >> 16);
    int pA = (int)(pre & 0xffffu), pB = (int)(pre >> 16);
#pragma unroll
    for (int i = 0; i < 8; ++i) {
      const unsigned pa = pk_a[i], pb = pk_b[i];
      const int jb = 2 * lane + 128 * i;
      if (maskA & (1u << (2 * i))) {
        if (pA < 64) plist[qa][pA] = ((unsigned)jb << 16) | (pa & 0xffffu);
        ++pA;
      }
      if (maskA & (2u << (2 * i))) {
        if (pA < 64) plist[qa][pA] = ((unsigned)(jb + 1) << 16) | (pa >> 16);
        ++pA;
      }
      if (maskB & (1u << (2 * i))) {
        if (pB < 64) plist[qb2][pB] = ((unsigned)jb << 16) | (pb & 0xffffu);
        ++pB;
      }
      if (maskB & (2u << (2 * i))) {
        if (pB < 64) plist[qb2][pB] = ((unsigned)(jb + 1) << 16) | (pb >> 16);
        ++pB;
      }
    }

    // rare fallback: >64 candidates -> bisection to tighter threshold
    if (__builtin_expect(ca > 64, 0)) {
      unsigned ans = 0u;
      int cge = ca;
      bool ex = false;
      for (int bit = 31; bit >= 0 && cge > 64 && !ex; --bit) {
        unsigned cand = ans | (1u << bit);
        float fc = keyinv(cand);
        int c = 0;
#pragma unroll
        for (int i = 0; i < 16; ++i)
          c += (int)__popcll(__ballot((float)sa[lane + 64 * i] >= fc));
        if (c >= U_TOP) { ans = cand; cge = c; ex = (c == U_TOP); }
      }
      float fa2 = keyinv(ans);
      int cc = 0;
#pragma unroll
      for (int i = 0; i < 16; ++i) {
        float va = (float)sa[lane + 64 * i];
        bool ka = va >= fa2;
        unsigned long long ma = __ballot(ka);
        if (ka) {
          int p = cc + mbcnt64(ma);
          if (p < 64)
            plist[qa][p] = ((unsigned)(lane + 64 * i) << 16) | h2u(va);
        }
        cc += (int)__popcll(ma);
      }
      ca = cc;
    }
    if (__builtin_expect(cb > 64, 0)) {
      unsigned ans = 0u;
      int cge = cb;
      bool ex = false;
      for (int bit = 31; bit >= 0 && cge > 64 && !ex; --bit) {
        unsigned cand = ans | (1u << bit);
        float fc = keyinv(cand);
        int c = 0;
#pragma unroll
        for (int i = 0; i < 16; ++i)
          c += (int)__popcll(__ballot((float)sb[lane + 64 * i] >= fc));
        if (c >= U_TOP) { ans = cand; cge = c; ex = (c == U_TOP); }
      }
      float fb2 = keyinv(ans);
      int cc = 0;
#pragma unroll
      for (int i = 0; i < 16; ++i) {
        float vb = (float)sb[lane + 64 * i];
        bool kb = vb >= fb2;
        unsigned long long mb = __ballot(kb);
        if (kb) {
          int p = cc + mbcnt64(mb);
          if (p < 64)
            plist[qb2][p] = ((unsigned)(lane + 64 * i) << 16) | h2u(vb);
        }
        cc += (int)__popcll(mb);
      }
      cb = cc;
    }
    ca = ca > 64 ? 64 : ca;
    cb = cb > 64 ? 64 : cb;

    // one candidate per lane; bisection over candidate keys -> exact 34th
    const unsigned pua = (lane < ca) ? plist[qa][lane] : 0u;
    const unsigned pub = (lane < cb) ? plist[qb2][lane] : 0u;
    const unsigned k2a = (lane < ca) ? okey16(pua & 0xffffu) : 0u;
    const unsigned k2b = (lane < cb) ? okey16(pub & 0xffffu) : 0u;
    unsigned an2A = 0u, an2B = 0u;
#pragma unroll
    for (int bit = 15; bit >= 0; --bit) {
      const unsigned cA = an2A | (1u << bit);
      const unsigned cB = an2B | (1u << bit);
      const int cntA = (int)__popcll(__ballot(k2a >= cA));
      const int cntB = (int)__popcll(__ballot(k2b >= cB));
      if (cntA >= U_TOP) an2A = cA;
      if (cntB >= U_TOP) an2B = cB;
    }
    const _Float16 tha = u2h16(ikey16(an2A));
    const _Float16 thb = u2h16(ikey16(an2B));

    // final keep set; exp only now
    const bool keepa = (lane < ca) && (u2h16((unsigned short)pua) >= tha);
    const bool keepb = (lane < cb) && (u2h16((unsigned short)pub) >= thb);
    unsigned long long kma = __ballot(keepa);
    unsigned long long kmb = __ballot(keepb);
    const int na = (int)__popcll(kma), nb = (int)__popcll(kmb);
    float ea = keepa ? __expf((float)u2h16((unsigned short)pua) - mxa) : 0.f;
    float eb = keepb ? __expf((float)u2h16((unsigned short)pub) - mxb) : 0.f;
    float za = ea, zb = eb;
#pragma unroll
    for (int off = 32; off; off >>= 1) {
      za += __shfl_xor(za, off);
      zb += __shfl_xor(zb, off);
    }
    if (keepa) plist[qa][mbcnt64(kma)] = (pua & 0xffff0000u) | h2u(ea);
    if (keepb) plist[qb2][mbcnt64(kmb)] = (pub & 0xffff0000u) | h2u(eb);

    // ---- sparse PV: 4 entry-slots x 16 dim-groups, dwordx2 loads ----
    const ushort_t* vbase = Vb + (size_t)b * SEQ * DMODEL + h * DK;
    const int slot = lane >> 4;   // 0..3: which entry within a 4-block
    const int dgrp = lane & 15;   // dims [4*dgrp, 4*dgrp+4)
    const int d4 = dgrp * 4;
    float aA0 = 0.f, aA1 = 0.f, aA2 = 0.f, aA3 = 0.f;
    float aB0 = 0.f, aB1 = 0.f, aB2 = 0.f, aB3 = 0.f;
    const int nmax = na > nb ? na : nb;
    for (int i = slot; i < nmax; i += 4) {
      const unsigned ua = (i < na) ? plist[qa][i] : 0u;   // weight 0 if OOB
      const unsigned ub = (i < nb) ? plist[qb2][i] : 0u;
      const uint2 va =
          *(const uint2*)(vbase + (size_t)(ua >> 16) * DMODEL + d4);
      const uint2 vb =
          *(const uint2*)(vbase + (size_t)(ub >> 16) * DMODEL + d4);
      const float wa = (float)u2h16((unsigned short)ua);
      const float wb = (float)u2h16((unsigned short)ub);
      aA0 += wa * __uint_as_float(va.x << 16);
      aA1 += wa * __uint_as_float(va.x & 0xffff0000u);
      aA2 += wa * __uint_as_float(va.y << 16);
      aA3 += wa * __uint_as_float(va.y & 0xffff0000u);
      aB0 += wb * __uint_as_float(vb.x << 16);
      aB1 += wb * __uint_as_float(vb.x & 0xffff0000u);
      aB2 += wb * __uint_as_float(vb.y << 16);
      aB3 += wb * __uint_as_float(vb.y & 0xffff0000u);
    }
    // reduce over the 4 entry-slots (lanes g, g+16, g+32, g+48)
    aA0 += __shfl_xor(aA0, 16); aA0 += __shfl_xor(aA0, 32);
    aA1 += __shfl_xor(aA1, 16); aA1 += __shfl_xor(aA1, 32);
    aA2 += __shfl_xor(aA2, 16); aA2 += __shfl_xor(aA2, 32);
    aA3 += __shfl_xor(aA3, 16); aA3 += __shfl_xor(aA3, 32);
    aB0 += __shfl_xor(aB0, 16); aB0 += __shfl_xor(aB0, 32);
    aB1 += __shfl_xor(aB1, 16); aB1 += __shfl_xor(aB1, 32);
    aB2 += __shfl_xor(aB2, 16); aB2 += __shfl_xor(aB2, 32);
    aB3 += __shfl_xor(aB3, 16); aB3 += __shfl_xor(aB3, 32);

    const float iza = 1.f / za, izb = 1.f / zb;
    if (slot == 0) {
      uint2 o;
      o.x = (unsigned)f2bf(aA0 * iza) | ((unsigned)f2bf(aA1 * iza) << 16);
      o.y = (unsigned)f2bf(aA2 * iza) | ((unsigned)f2bf(aA3 * iza) << 16);
      *(uint2*)(Ob + (size_t)(b * SEQ + q0 + qa) * DMODEL + h * DK + d4) = o;
    } else if (slot == 1) {
      uint2 o;
      o.x = (unsigned)f2bf(aB0 * izb) | ((unsigned)f2bf(aB1 * izb) << 16);
      o.y = (unsigned)f2bf(aB2 * izb) | ((unsigned)f2bf(aB3 * izb) << 16);
      *(uint2*)(Ob + (size_t)(b * SEQ + q0 + qb2) * DMODEL + h * DK + d4) = o;
    }
  }
}

// ---------------------------------------------------------------------------
// Orchestration (verified-best config, 488.0 us).  ws layout (MiB):
// ffh/qkv [0,16) (Wo partials reuse [0,8) after attn) | ao [16,20)
// (xb pre-loop; FFN2 partials reuse [16,24)) | [20,24) FFN2 partial 1 |
// hb [24,28) | wt [28, 46.2).
// Layer GEMMs: BK=64 2-phase dbuf. FFN1 BN=128 (512 blk); QKV BN=64
// (768 blk); Wo/FFN2 split-K BN=64 (512 blk each).
// ---------------------------------------------------------------------------
extern "C" void kernel_launch(void* const* d_in, const int* in_sizes, int n_in,
                              void* d_out, int out_size, void* d_ws,
                              size_t ws_size, hipStream_t stream) {
  const float* x = (const float*)d_in[0];
  const float* W_emb = (const float*)d_in[1];
  const float* b_emb = (const float*)d_in[2];
  const float* Wq = (const float*)d_in[3];
  const float* bq = (const float*)d_in[4];
  const float* Wk = (const float*)d_in[5];
  const float* bk = (const float*)d_in[6];
  const float* Wv = (const float*)d_in[7];
  const float* bv = (const float*)d_in[8];
  const float* Wo = (const float*)d_in[9];
  const float* bo = (const float*)d_in[10];
  const float* ln1_g = (const float*)d_in[11];
  const float* ln1_b = (const float*)d_in[12];
  const float* W1 = (const float*)d_in[13];
  const float* b1 = (const float*)d_in[14];
  const float* W2 = (const float*)d_in[15];
  const float* b2 = (const float*)d_in[16];
  const float* ln2_g = (const float*)d_in[17];
  const float* ln2_b = (const float*)d_in[18];
  const float* W_dec = (const float*)d_in[19];
  const float* b_dec = (const float*)d_in[20];

  char* wsb = (char*)d_ws;
  ushort_t* qkv = (ushort_t*)wsb;
  ushort_t* ffh = (ushort_t*)wsb;
  ushort_t* wop = (ushort_t*)wsb;  // Wo partials [0,8M)
  ushort_t* ao = (ushort_t*)(wsb + ((size_t)16 << 20));
  ushort_t* xb = (ushort_t*)(wsb + ((size_t)16 << 20));
  ushort_t* ffp = (ushort_t*)(wsb + ((size_t)16 << 20));  // FFN2 partials
  ushort_t* hb = (ushort_t*)(wsb + ((size_t)24 << 20));
  short* wt = (short*)(wsb + ((size_t)28 << 20));
  short* wembT = wt + 9437184;
  short* wdecT = wt + 9502720;

  f32_to_bf16_kernel<<<dim3(512), 256, 0, stream>>>(x, xb);
  convert_all<<<dim3(9312), dim3(32, 8), 0, stream>>>(Wq, Wk, Wv, Wo, W1, W2,
                                                      W_emb, W_dec, wt);
  // embed: hb = bf16((xb @ W_emb + b_emb)*sqrt(512) + PE)
  gemm64<0, 1, 2, 0><<<dim3(8, 64), 256, 0, stream>>>(
      xb, wembT, b_emb, (void*)hb, nullptr, 128, 512);

  for (int i = 0; i < 3; ++i) {
    short* wtL = wt + (size_t)i * 3145728;

    // QKV: one N=1536 GEMM on 128x64 tiles (768 blocks, 3/CU)
    gemmT<0, 1, 64><<<dim3(24, 32), 256, 0, stream>>>(
        hb, wtL, bq + i * DMODEL, bk + i * DMODEL, bv + i * DMODEL, qkv, 512,
        512, 2097152);

    attn_kernel<<<dim3(SEQ / 16, NHEAD, BATCH), dim3(512), 0, stream>>>(
        qkv, qkv + 2097152, qkv + 4194304, ao);

    // Wo split-K (K=512 -> 2x256), 128x64 tiles (512 blocks, 2/CU)
    gemmskT<64><<<dim3(8, 32, 2), 256, 0, stream>>>(
        ao, wtL + 786432, bo + i * DMODEL, wop, 512, 256);
    ln_red_kernel<<<dim3(ROWS / 4), 256, 0, stream>>>(
        wop, wop + 2097152, ln1_g + i * DMODEL, ln1_b + i * DMODEL, hb);

    // FFN1 N=2048 on 128x128 tiles (512 blocks, 2/CU, 250B staged/MFMA)
    gemmT<1, 0, 128><<<dim3(16, 32), 256, 0, stream>>>(
        hb, wtL + 1048576, b1 + i * DFF, nullptr, nullptr, ffh, 512, 2048, 0);
    // FFN2 split-K (K=2048 -> 2x1024), 128x64 tiles (512 blocks, 2/CU)
    gemmskT<64><<<dim3(8, 32, 2), 256, 0, stream>>>(
        ffh, wtL + 2097152, b2 + i * DMODEL, ffp, 2048, 1024);
    ln_red_kernel<<<dim3(ROWS / 4), 256, 0, stream>>>(
        ffp, ffp + 2097152, ln2_g + i * DMODEL, ln2_b + i * DMODEL, hb);
  }

  gemm64<0, 0, 0, 0><<<dim3(1, 64), 256, 0, stream>>>(
      hb, wdecT, b_dec, d_out, nullptr, 512, 64);
}